// Round 18
// baseline (335.277 us; speedup 1.0000x reference)
//
#include <hip/hip_runtime.h>
#include <hip/hip_bf16.h>

#define NBATCH 8
#define HEIGHT 48
#define WIDTH  48
#define DMODEL 512
#define DSTATE 16
#define DTRANK 8
#define DINNER 1024
#define LSEQ   (HEIGHT*WIDTH)     // 2304
#define NROWS  (NBATCH*LSEQ)      // 18432
#define NXP    40                 // DTRANK + 2*DSTATE
#define NCH    128                // chunks per sequence
#define TCH    18                 // LSEQ / NCH

typedef unsigned short u16;
typedef unsigned int   u32;
typedef __attribute__((ext_vector_type(8))) short short8;
typedef __attribute__((ext_vector_type(4))) float f32x4;

__device__ __forceinline__ float bf2f(u16 u) {
    u32 x = ((u32)u) << 16;
    return __uint_as_float(x);
}
__device__ __forceinline__ u16 f2bf(float f) {
    u32 x = __float_as_uint(f);
    u32 r = (x + 0x7FFFu + ((x >> 16) & 1u)) >> 16;
    return (u16)r;
}

#if __has_builtin(__builtin_amdgcn_exp2f)
__device__ __forceinline__ float EXP2(float x) { return __builtin_amdgcn_exp2f(x); }
#else
__device__ __forceinline__ float EXP2(float x) { return __expf(x * 0.69314718f); }
#endif

#define GLD16(g, l) __builtin_amdgcn_global_load_lds( \
    (const __attribute__((address_space(1))) void*)(g), \
    (__attribute__((address_space(3))) void*)(l), 16, 0, 0)

// ---------------------------------------------------------------------------
// P0: merged prep: x (f32)->xbf (bf16), and the 4 weight preps.
// ---------------------------------------------------------------------------
__global__ __launch_bounds__(256) void k_prep(const float* __restrict__ x,
                                              const float* __restrict__ W_in,
                                              const float* __restrict__ W_out,
                                              const float* __restrict__ W_xproj,
                                              const float* __restrict__ W_dtN,
                                              u16* __restrict__ xbf,
                                              u16* __restrict__ WinT,
                                              u16* __restrict__ WoutT,
                                              u16* __restrict__ WxpB,
                                              u16* __restrict__ WdtNB) {
    if (blockIdx.x < 9216) {
        int i = blockIdx.x * 256 + threadIdx.x;
        float4 v = *reinterpret_cast<const float4*>(x + (size_t)i * 4);
        ushort4 o;
        o.x = f2bf(v.x); o.y = f2bf(v.y); o.z = f2bf(v.z); o.w = f2bf(v.w);
        *reinterpret_cast<ushort4*>(xbf + (size_t)i * 4) = o;
        return;
    }
    int idx = (blockIdx.x - 9216) * 256 + threadIdx.x;
    if (idx < 2048 * 512) {
        int n = idx >> 9, k = idx & 511;
        WinT[idx] = f2bf(W_in[(size_t)k * 2048 + n]);
    } else if (idx < 2048 * 512 + 512 * 1024) {
        int j = idx - 2048 * 512;
        int n = j >> 10, k = j & 1023;
        WoutT[j] = f2bf(W_out[(size_t)k * 512 + n]);
    } else if (idx < 2048 * 512 + 512 * 1024 + 48 * 1024) {
        int j = idx - (2048 * 512 + 512 * 1024);
        int n = j >> 10, k = j & 1023;
        WxpB[j] = (n < NXP) ? f2bf(W_xproj[(size_t)k * NXP + n]) : (u16)0;
    } else {
        int j = idx - (2048 * 512 + 512 * 1024 + 48 * 1024);
        int n = j >> 10, k = j & 1023;
        WdtNB[j] = f2bf(W_dtN[(size_t)k * DSTATE + n]);
    }
}

// ---------------------------------------------------------------------------
// K1/K6: bf16 MFMA GEMM, 128x128 tile, BK=32, 4 waves (2x2), 4x4 fragments.
// XCD-aware block swizzle.
// ---------------------------------------------------------------------------
template<int K, int LDA, int LDB, int LDC, bool F32OUT>
__global__ __launch_bounds__(256) void k_gemm_mfma(const u16* __restrict__ A,
                                                   const u16* __restrict__ B,
                                                   const float* __restrict__ bias,
                                                   void* __restrict__ Cv) {
    __shared__ u16 As[128 * 32];
    __shared__ u16 Bs[128 * 32];
    const int tid = threadIdx.x;
    const int l   = tid & 63;
    const int w   = tid >> 6;
    const int wm  = w >> 1, wn = w & 1;
    const int id   = blockIdx.y * gridDim.x + blockIdx.x;
    const int nwg  = gridDim.x * gridDim.y;
    const int swz  = (id & 7) * (nwg >> 3) + (id >> 3);
    const int bx   = swz % gridDim.x;
    const int by   = swz / gridDim.x;
    const int m0  = by * 128, n0 = bx * 128;
    const int srow = w * 32 + (l >> 2);
    const int sc   = l & 3;
    const int kh = l >> 4;
    const int lr = l & 15;

    f32x4 acc[4][4];
#pragma unroll
    for (int i = 0; i < 4; ++i)
#pragma unroll
        for (int j = 0; j < 4; ++j)
            acc[i][j] = (f32x4){0.f, 0.f, 0.f, 0.f};

    for (int k0 = 0; k0 < K; k0 += 32) {
#pragma unroll
        for (int i = 0; i < 2; ++i) {
            int r  = srow + i * 16;
            int cg = sc ^ ((r >> 1) & 3);
            const u16* ga = A + (size_t)(m0 + r) * LDA + k0 + cg * 8;
            const u16* gb = B + (size_t)(n0 + r) * LDB + k0 + cg * 8;
            GLD16(ga, As + (w * 2 + i) * 512);
            GLD16(gb, Bs + (w * 2 + i) * 512);
        }
        __syncthreads();
        short8 af[4], bfr[4];
#pragma unroll
        for (int f = 0; f < 4; ++f) {
            int ar = wm * 64 + f * 16 + lr;
            af[f]  = *reinterpret_cast<const short8*>(As + ar * 32 + ((kh ^ ((ar >> 1) & 3)) * 8));
            int br = wn * 64 + f * 16 + lr;
            bfr[f] = *reinterpret_cast<const short8*>(Bs + br * 32 + ((kh ^ ((br >> 1) & 3)) * 8));
        }
#pragma unroll
        for (int fm = 0; fm < 4; ++fm)
#pragma unroll
            for (int fn = 0; fn < 4; ++fn)
                acc[fm][fn] = __builtin_amdgcn_mfma_f32_16x16x32_bf16(
                    af[fm], bfr[fn], acc[fm][fn], 0, 0, 0);
        __syncthreads();
    }

#pragma unroll
    for (int fm = 0; fm < 4; ++fm) {
#pragma unroll
        for (int r = 0; r < 4; ++r) {
            int row = m0 + wm * 64 + fm * 16 + (l >> 4) * 4 + r;
#pragma unroll
            for (int fn = 0; fn < 4; ++fn) {
                int col = n0 + wn * 64 + fn * 16 + lr;
                if (F32OUT) {
                    ((float*)Cv)[(size_t)row * LDC + col] = acc[fm][fn][r] + bias[col];
                } else {
                    ((u16*)Cv)[(size_t)row * LDC + col] = f2bf(acc[fm][fn][r]);
                }
            }
        }
    }
}

// ---------------------------------------------------------------------------
// K2: depthwise 3x3 SAME conv, 2h x 8w blocking.
// ---------------------------------------------------------------------------
__global__ __launch_bounds__(256) void k_conv(const u16* __restrict__ xz,
                                              const float* __restrict__ ck,
                                              u16* __restrict__ xc) {
    const int blk = blockIdx.x;
    const int wg = blk % (WIDTH / 8);
    const int rest = blk / (WIDTH / 8);
    const int hp = rest % (HEIGHT / 2);
    const int b = rest / (HEIGHT / 2);
    const int h0 = hp * 2;
    const int w0 = wg * 8;
    const int c0 = threadIdx.x * 4;

    float acc[16][4];
#pragma unroll
    for (int j = 0; j < 16; ++j)
#pragma unroll
        for (int q = 0; q < 4; ++q) acc[j][q] = 0.f;

#pragma unroll
    for (int i = 0; i < 4; ++i) {
        int hh = h0 - 1 + i;
        if (hh < 0 || hh >= HEIGHT) continue;
        const u16* rp = xz + ((size_t)(b * HEIGHT + hh) * WIDTH) * 2048 + c0;
        float a[10][4];
#pragma unroll
        for (int p = 0; p < 10; ++p) {
            int ww = w0 - 1 + p;
            if (ww >= 0 && ww < WIDTH) {
                ushort4 v = *reinterpret_cast<const ushort4*>(rp + (size_t)ww * 2048);
                a[p][0] = bf2f(v.x); a[p][1] = bf2f(v.y);
                a[p][2] = bf2f(v.z); a[p][3] = bf2f(v.w);
            } else {
                a[p][0] = a[p][1] = a[p][2] = a[p][3] = 0.f;
            }
        }
#pragma unroll
        for (int oh = 0; oh < 2; ++oh) {
            int kh = i - oh;
            if (kh < 0 || kh > 2) continue;
#pragma unroll
            for (int kw = 0; kw < 3; ++kw) {
                float4 kv = *reinterpret_cast<const float4*>(ck + (kh * 3 + kw) * DINNER + c0);
#pragma unroll
                for (int j = 0; j < 8; ++j) {
                    acc[oh * 8 + j][0] = fmaf(a[j + kw][0], kv.x, acc[oh * 8 + j][0]);
                    acc[oh * 8 + j][1] = fmaf(a[j + kw][1], kv.y, acc[oh * 8 + j][1]);
                    acc[oh * 8 + j][2] = fmaf(a[j + kw][2], kv.z, acc[oh * 8 + j][2]);
                    acc[oh * 8 + j][3] = fmaf(a[j + kw][3], kv.w, acc[oh * 8 + j][3]);
                }
            }
        }
    }
#pragma unroll
    for (int oh = 0; oh < 2; ++oh) {
        const size_t orow = (size_t)((b * HEIGHT + h0 + oh) * WIDTH + w0);
#pragma unroll
        for (int j = 0; j < 8; ++j) {
            ushort4 ov;
            ov.x = f2bf(acc[oh * 8 + j][0]); ov.y = f2bf(acc[oh * 8 + j][1]);
            ov.z = f2bf(acc[oh * 8 + j][2]); ov.w = f2bf(acc[oh * 8 + j][3]);
            *reinterpret_cast<ushort4*>(xc + (orow + j) * DINNER + c0) = ov;
        }
    }
}

// ---------------------------------------------------------------------------
// K3a: xp = xc @ WxpB^T via MFMA. M-tile=64, N=48, K=1024.
// ---------------------------------------------------------------------------
__global__ __launch_bounds__(256) void k_xproj(const u16* __restrict__ xc,
                                               const u16* __restrict__ WxpB,
                                               float* __restrict__ xp_out) {
    __shared__ u16 As[64 * 32];
    __shared__ u16 Bs[48 * 32];
    const int tid = threadIdx.x;
    const int l = tid & 63;
    const int w = tid >> 6;
    const int m0 = blockIdx.x * 64;
    const int kh = l >> 4, lr = l & 15;
    const int srow = w * 16 + (l >> 2);
    const int sc = l & 3;

    f32x4 acc[3];
    acc[0] = acc[1] = acc[2] = (f32x4){0.f, 0.f, 0.f, 0.f};

    for (int k0 = 0; k0 < 1024; k0 += 32) {
        {
            int cg = sc ^ ((srow >> 1) & 3);
            GLD16(xc + (size_t)(m0 + srow) * DINNER + k0 + cg * 8, As + w * 512);
            if (w < 3)
                GLD16(WxpB + (size_t)srow * 1024 + k0 + cg * 8, Bs + w * 512);
        }
        __syncthreads();
        int ar = w * 16 + lr;
        short8 af = *reinterpret_cast<const short8*>(As + ar * 32 + ((kh ^ ((ar >> 1) & 3)) * 8));
#pragma unroll
        for (int fn = 0; fn < 3; ++fn) {
            int br = fn * 16 + lr;
            short8 bf = *reinterpret_cast<const short8*>(Bs + br * 32 + ((kh ^ ((br >> 1) & 3)) * 8));
            acc[fn] = __builtin_amdgcn_mfma_f32_16x16x32_bf16(af, bf, acc[fn], 0, 0, 0);
        }
        __syncthreads();
    }
#pragma unroll
    for (int fn = 0; fn < 3; ++fn)
#pragma unroll
        for (int r = 0; r < 4; ++r) {
            int row = m0 + w * 16 + (l >> 4) * 4 + r;
            int col = fn * 16 + lr;
            if (col < NXP) xp_out[(size_t)row * NXP + col] = acc[fn][r];
        }
}

// ---------------------------------------------------------------------------
// K3b: dt = softplus(xp[:, :8] @ W_dt + b_dt) -> bf16 [row][1024]
// ---------------------------------------------------------------------------
__global__ __launch_bounds__(256) void k_dt(const float* __restrict__ xp,
                                            const float* __restrict__ W_dt,
                                            const float* __restrict__ b_dt,
                                            u16* __restrict__ dt_out) {
    int gid = blockIdx.x * 256 + threadIdx.x;
    int row = gid >> 7;
    int dj  = (gid & 127) * 8;
    const float* xr = xp + (size_t)row * NXP;
    float4 xa = *reinterpret_cast<const float4*>(xr);
    float4 xb = *reinterpret_cast<const float4*>(xr + 4);
    float xv[8] = {xa.x, xa.y, xa.z, xa.w, xb.x, xb.y, xb.z, xb.w};
    float a[8];
    {
        float4 b0 = *reinterpret_cast<const float4*>(b_dt + dj);
        float4 b1 = *reinterpret_cast<const float4*>(b_dt + dj + 4);
        a[0]=b0.x; a[1]=b0.y; a[2]=b0.z; a[3]=b0.w;
        a[4]=b1.x; a[5]=b1.y; a[6]=b1.z; a[7]=b1.w;
    }
#pragma unroll
    for (int j = 0; j < 8; ++j) {
        float4 w0 = *reinterpret_cast<const float4*>(W_dt + j * DINNER + dj);
        float4 w1 = *reinterpret_cast<const float4*>(W_dt + j * DINNER + dj + 4);
        a[0] = fmaf(xv[j], w0.x, a[0]); a[1] = fmaf(xv[j], w0.y, a[1]);
        a[2] = fmaf(xv[j], w0.z, a[2]); a[3] = fmaf(xv[j], w0.w, a[3]);
        a[4] = fmaf(xv[j], w1.x, a[4]); a[5] = fmaf(xv[j], w1.y, a[5]);
        a[6] = fmaf(xv[j], w1.z, a[6]); a[7] = fmaf(xv[j], w1.w, a[7]);
    }
    short8 o;
#pragma unroll
    for (int j = 0; j < 8; ++j) {
        float dt = fmaxf(a[j], 0.f) + log1pf(__expf(-fabsf(a[j])));
        o[j] = (short)f2bf(dt);
    }
    *reinterpret_cast<short8*>(dt_out + (size_t)row * DINNER + dj) = o;
}

// ---------------------------------------------------------------------------
// K3c: dtN = dt @ WdtNB^T + b_dtN via MFMA (M-tile=64, N=16, K=1024), then
// fused epilogue writes dnBC[row][32] = { dtN*B , C } (f32).
// ---------------------------------------------------------------------------
__global__ __launch_bounds__(256) void k_dtn(const u16* __restrict__ dtb,
                                             const u16* __restrict__ WdtNB,
                                             const float* __restrict__ b_dtN,
                                             const float* __restrict__ xp,
                                             float* __restrict__ dnBC) {
    __shared__ u16 As[64 * 32];
    __shared__ u16 Bs[16 * 32];
    const int tid = threadIdx.x;
    const int l = tid & 63;
    const int w = tid >> 6;
    const int m0 = blockIdx.x * 64;
    const int kh = l >> 4, lr = l & 15;
    const int srow = w * 16 + (l >> 2);
    const int sc = l & 3;

    f32x4 acc = (f32x4){0.f, 0.f, 0.f, 0.f};

    for (int k0 = 0; k0 < 1024; k0 += 32) {
        {
            int cg = sc ^ ((srow >> 1) & 3);
            GLD16(dtb + (size_t)(m0 + srow) * DINNER + k0 + cg * 8, As + w * 512);
            if (w == 0)
                GLD16(WdtNB + (size_t)srow * 1024 + k0 + cg * 8, Bs);
        }
        __syncthreads();
        int ar = w * 16 + lr;
        short8 af = *reinterpret_cast<const short8*>(As + ar * 32 + ((kh ^ ((ar >> 1) & 3)) * 8));
        short8 bf = *reinterpret_cast<const short8*>(Bs + lr * 32 + ((kh ^ ((lr >> 1) & 3)) * 8));
        acc = __builtin_amdgcn_mfma_f32_16x16x32_bf16(af, bf, acc, 0, 0, 0);
        __syncthreads();
    }
    float bn = b_dtN[lr];
#pragma unroll
    for (int r = 0; r < 4; ++r) {
        int row = m0 + w * 16 + (l >> 4) * 4 + r;
        float dn = acc[r] + bn;
        float Bv = xp[(size_t)row * NXP + DTRANK + lr];
        float Cv = xp[(size_t)row * NXP + DTRANK + DSTATE + lr];
        dnBC[(size_t)row * 32 + lr]      = dn * Bv;
        dnBC[(size_t)row * 32 + 16 + lr] = Cv;
    }
}

// ---------------------------------------------------------------------------
// K4a: chunk-local scan; lane = d, 16 states in registers; A/B-rotated
// 1-iteration register prefetch of dt/xc. Q stored bf16. NCH=128.
// ---------------------------------------------------------------------------
#define P1_N(IDX, COMP) \
    dA = EXP2(dt * An2[IDX]); h[IDX] = fmaf(dA, h[IDX], COMP * xt);

#define P1_BODY(T, DTC, XCC, DTN, XCN, PR) { \
    const float4* sv = pS + (size_t)(T) * 8; \
    float4 u0 = sv[0], u1 = sv[1], u2 = sv[2], u3 = sv[3]; \
    if (PR) { DTN = pdt[(size_t)((T) + 1) * DINNER]; \
              XCN = pxc[(size_t)((T) + 1) * DINNER]; } \
    float dt = bf2f(DTC), xt = bf2f(XCC); \
    sdt += dt; \
    float dA; \
    P1_N(0,  u0.x) P1_N(1,  u0.y) P1_N(2,  u0.z) P1_N(3,  u0.w) \
    P1_N(4,  u1.x) P1_N(5,  u1.y) P1_N(6,  u1.z) P1_N(7,  u1.w) \
    P1_N(8,  u2.x) P1_N(9,  u2.y) P1_N(10, u2.z) P1_N(11, u2.w) \
    P1_N(12, u3.x) P1_N(13, u3.y) P1_N(14, u3.z) P1_N(15, u3.w) }

__global__ __launch_bounds__(256) void k_scan_p1(const u16* __restrict__ xc,
                                                 const u16* __restrict__ dtb,
                                                 const float* __restrict__ dnBC,
                                                 const float* __restrict__ A_log,
                                                 float* __restrict__ sdt_out,
                                                 u16* __restrict__ Qbuf) {
    const int tid = threadIdx.x;
    const int id  = blockIdx.x;
    const int swz = (id & 7) * ((NBATCH * NCH * 4) >> 3) + (id >> 3);
    const int quarter = swz & 3;
    const int bc = swz >> 2;            // b*NCH + c
    const int c = bc & (NCH - 1);
    const int b = bc >> 7;
    const int d = quarter * 256 + tid;

    float An2[16];
#pragma unroll
    for (int n = 0; n < 16; ++n)
        An2[n] = -__expf(A_log[n]) * 1.44269504f;   // A_n * log2(e)

    float h[16];
#pragma unroll
    for (int n = 0; n < 16; ++n) h[n] = 0.f;
    float sdt = 0.f;

    const size_t row0 = (size_t)b * LSEQ + (size_t)c * TCH;
    const u16* pdt = dtb + row0 * DINNER + d;
    const u16* pxc = xc  + row0 * DINNER + d;
    const float4* pS = reinterpret_cast<const float4*>(dnBC + row0 * 32);

    u16 dtA = pdt[0], xcA = pxc[0];
    u16 dtB, xcB;

    for (int t = 0; t < TCH - 2; t += 2) {
        P1_BODY(t,     dtA, xcA, dtB, xcB, true)
        P1_BODY(t + 1, dtB, xcB, dtA, xcA, true)
    }
    P1_BODY(TCH - 2, dtA, xcA, dtB, xcB, true)
    P1_BODY(TCH - 1, dtB, xcB, dtA, xcA, false)

    sdt_out[(size_t)bc * DINNER + d] = sdt;
    size_t base = ((size_t)bc << 14) + d;   // [bc][n][d]
#pragma unroll
    for (int n = 0; n < 16; ++n)
        Qbuf[base + (size_t)n * DINNER] = f2bf(h[n]);
}

// ---------------------------------------------------------------------------
// K4b: combine chunk states. thread = (b, n, d); NCH sequential steps.
// P recomputed from sdt; Q in bf16 (combine itself in f32).
// ---------------------------------------------------------------------------
__global__ __launch_bounds__(256) void k_scan_p2(const float* __restrict__ sdt,
                                                 const float* __restrict__ A_log,
                                                 u16* __restrict__ Qbuf) {
    int tid = blockIdx.x * 256 + threadIdx.x;
    int b = tid >> 14, rem = tid & 16383;
    int n = rem >> 10, d = rem & 1023;
    float An2 = -__expf(A_log[n]) * 1.44269504f;
    float h = 0.f;
    for (int c = 0; c < NCH; ++c) {
        int bc = b * NCH + c;
        float P = EXP2(sdt[(size_t)bc * DINNER + d] * An2);
        size_t idx = ((size_t)bc << 14) + rem;
        float q = bf2f(Qbuf[idx]);
        Qbuf[idx] = f2bf(h);           // h_start for chunk c
        h = fmaf(P, h, q);
    }
}

// ---------------------------------------------------------------------------
// K4c: re-run chunk from true h_start; A/B-rotated register prefetch;
// y = C·h + D*x written to xz y-half. Q in bf16. NCH=128.
// ---------------------------------------------------------------------------
#define P3_N(IDX, UC, CC, YS) \
    dA = EXP2(dt * An2[IDX]); h[IDX] = fmaf(dA, h[IDX], UC * xt); \
    YS = fmaf(h[IDX], CC, YS);

#define P3_BODY(T, DTC, XCC, DTN, XCN, PR) { \
    const float4* sv = pS + (size_t)(T) * 8; \
    float4 u0 = sv[0], u1 = sv[1], u2 = sv[2], u3 = sv[3]; \
    float4 c4 = sv[4], c5 = sv[5], c6 = sv[6], c7 = sv[7]; \
    if (PR) { DTN = pdt[(size_t)((T) + 1) * DINNER]; \
              XCN = pxc[(size_t)((T) + 1) * DINNER]; } \
    float dt = bf2f(DTC), xt = bf2f(XCC); \
    float ys0 = Dsk * xt, ys1 = 0.f, ys2 = 0.f, ys3 = 0.f; \
    float dA; \
    P3_N(0,  u0.x, c4.x, ys0) P3_N(1,  u0.y, c4.y, ys1) \
    P3_N(2,  u0.z, c4.z, ys2) P3_N(3,  u0.w, c4.w, ys3) \
    P3_N(4,  u1.x, c5.x, ys0) P3_N(5,  u1.y, c5.y, ys1) \
    P3_N(6,  u1.z, c5.z, ys2) P3_N(7,  u1.w, c5.w, ys3) \
    P3_N(8,  u2.x, c6.x, ys0) P3_N(9,  u2.y, c6.y, ys1) \
    P3_N(10, u2.z, c6.z, ys2) P3_N(11, u2.w, c6.w, ys3) \
    P3_N(12, u3.x, c7.x, ys0) P3_N(13, u3.y, c7.y, ys1) \
    P3_N(14, u3.z, c7.z, ys2) P3_N(15, u3.w, c7.w, ys3) \
    ybuf[(row0 + (T)) * 2048 + d] = f2bf((ys0 + ys1) + (ys2 + ys3)); }

__global__ __launch_bounds__(256) void k_scan_p3(const u16* __restrict__ xc,
                                                 const u16* __restrict__ dtb,
                                                 const float* __restrict__ dnBC,
                                                 const float* __restrict__ A_log,
                                                 const float* __restrict__ Dskip,
                                                 const u16* __restrict__ Qbuf,
                                                 u16* __restrict__ ybuf) {
    const int tid = threadIdx.x;
    const int id  = blockIdx.x;
    const int swz = (id & 7) * ((NBATCH * NCH * 4) >> 3) + (id >> 3);
    const int quarter = swz & 3;
    const int bc = swz >> 2;
    const int c = bc & (NCH - 1);
    const int b = bc >> 7;
    const int d = quarter * 256 + tid;

    float An2[16];
#pragma unroll
    for (int n = 0; n < 16; ++n)
        An2[n] = -__expf(A_log[n]) * 1.44269504f;

    float h[16];
    size_t base = ((size_t)bc << 14) + d;   // [bc][n][d]
#pragma unroll
    for (int n = 0; n < 16; ++n) h[n] = bf2f(Qbuf[base + (size_t)n * DINNER]);
    float Dsk = Dskip[d];

    const size_t row0 = (size_t)b * LSEQ + (size_t)c * TCH;
    const u16* pdt = dtb + row0 * DINNER + d;
    const u16* pxc = xc  + row0 * DINNER + d;
    const float4* pS = reinterpret_cast<const float4*>(dnBC + row0 * 32);

    u16 dtA = pdt[0], xcA = pxc[0];
    u16 dtB, xcB;

    for (int t = 0; t < TCH - 2; t += 2) {
        P3_BODY(t,     dtA, xcA, dtB, xcB, true)
        P3_BODY(t + 1, dtB, xcB, dtA, xcA, true)
    }
    P3_BODY(TCH - 2, dtA, xcA, dtB, xcB, true)
    P3_BODY(TCH - 1, dtB, xcB, dtA, xcA, false)
}

// ---------------------------------------------------------------------------
// K5: LayerNorm(y) * ln_g + ln_b, then * silu(z). Wave-per-row.
// ---------------------------------------------------------------------------
__global__ __launch_bounds__(256) void k_ln_gate(u16* __restrict__ xz,
                                                 const float* __restrict__ ln_g,
                                                 const float* __restrict__ ln_b) {
    const int wv = threadIdx.x >> 6, l = threadIdx.x & 63;
    const int row = blockIdx.x * 4 + wv;
    u16* yrow = xz + (size_t)row * 2048;
    const int c0 = l * 16;

    short8 v0 = *reinterpret_cast<const short8*>(yrow + c0);
    short8 v1 = *reinterpret_cast<const short8*>(yrow + c0 + 8);
    float y[16];
#pragma unroll
    for (int j = 0; j < 8; ++j) {
        y[j]     = bf2f((u16)v0[j]);
        y[8 + j] = bf2f((u16)v1[j]);
    }
    float s = 0.f, q = 0.f;
#pragma unroll
    for (int j = 0; j < 16; ++j) { s += y[j]; q = fmaf(y[j], y[j], q); }
#pragma unroll
    for (int m = 32; m; m >>= 1) {
        s += __shfl_xor(s, m, 64);
        q += __shfl_xor(q, m, 64);
    }
    float mu = s * (1.f / DINNER);
    float var = q * (1.f / DINNER) - mu * mu;
    float rstd = rsqrtf(var + 1e-5f);

    short8 z0 = *reinterpret_cast<const short8*>(yrow + DINNER + c0);
    short8 z1 = *reinterpret_cast<const short8*>(yrow + DINNER + c0 + 8);
    float4 lg0 = *reinterpret_cast<const float4*>(ln_g + c0);
    float4 lg1 = *reinterpret_cast<const float4*>(ln_g + c0 + 4);
    float4 lg2 = *reinterpret_cast<const float4*>(ln_g + c0 + 8);
    float4 lg3 = *reinterpret_cast<const float4*>(ln_g + c0 + 12);
    float4 lb0 = *reinterpret_cast<const float4*>(ln_b + c0);
    float4 lb1 = *reinterpret_cast<const float4*>(ln_b + c0 + 4);
    float4 lb2 = *reinterpret_cast<const float4*>(ln_b + c0 + 8);
    float4 lb3 = *reinterpret_cast<const float4*>(ln_b + c0 + 12);
    float lg[16] = {lg0.x,lg0.y,lg0.z,lg0.w, lg1.x,lg1.y,lg1.z,lg1.w,
                    lg2.x,lg2.y,lg2.z,lg2.w, lg3.x,lg3.y,lg3.z,lg3.w};
    float lb[16] = {lb0.x,lb0.y,lb0.z,lb0.w, lb1.x,lb1.y,lb1.z,lb1.w,
                    lb2.x,lb2.y,lb2.z,lb2.w, lb3.x,lb3.y,lb3.z,lb3.w};

    short8 o0, o1;
#pragma unroll
    for (int j = 0; j < 16; ++j) {
        float zv = bf2f((u16)((j < 8) ? z0[j] : z1[j - 8]));
        float g = ((y[j] - mu) * rstd * lg[j] + lb[j]) * (zv / (1.f + __expf(-zv)));
        if (j < 8) o0[j] = (short)f2bf(g); else o1[j - 8] = (short)f2bf(g);
    }
    *reinterpret_cast<short8*>(yrow + c0)     = o0;
    *reinterpret_cast<short8*>(yrow + c0 + 8) = o1;
}

// ---------------------------------------------------------------------------
extern "C" void kernel_launch(void* const* d_in, const int* in_sizes, int n_in,
                              void* d_out, int out_size, void* d_ws, size_t ws_size,
                              hipStream_t stream) {
    const float* x       = (const float*)d_in[0];
    const float* W_in    = (const float*)d_in[1];
    const float* conv_k  = (const float*)d_in[2];
    const float* W_xproj = (const float*)d_in[3];
    const float* W_dt    = (const float*)d_in[4];
    const float* b_dt    = (const float*)d_in[5];
    const float* A_log   = (const float*)d_in[6];
    const float* Dskip   = (const float*)d_in[7];
    const float* W_dtN   = (const float*)d_in[8];
    const float* b_dtN   = (const float*)d_in[9];
    const float* ln_g    = (const float*)d_in[10];
    const float* ln_b    = (const float*)d_in[11];
    const float* W_out   = (const float*)d_in[12];
    const float* b_out   = (const float*)d_in[13];
    float* out = (float*)d_out;

    char* ws = (char*)d_ws;
    size_t off = 0;
    u16*   xz    = (u16*)(ws + off); off += (size_t)NROWS * 2048 * 2;   // 75.5 MB
    u16*   xc    = (u16*)(ws + off); off += (size_t)NROWS * 1024 * 2;   // 37.7 MB
    u16*   dtb   = (u16*)(ws + off); off += (size_t)NROWS * 1024 * 2;   // 37.7 MB
    float* dnBC  = (float*)(ws + off); off += (size_t)NROWS * 32 * 4;   // 2.36 MB
    // dead-at-scan span: xpb + WinT + WxpB + WdtNB (5.08 MB) -- sdt (4.19 MB)
    // overlays it (all four are consumed before k_scan_p1 runs).
    float* xpb   = (float*)(ws + off);
    float* sdtb  = xpb;
    off += (size_t)NROWS * NXP * 4;                                     // 2.95 MB
    u16*   WinT  = (u16*)(ws + off); off += (size_t)2048 * 512 * 2;     // 2.0 MB
    u16*   WxpB  = (u16*)(ws + off); off += (size_t)48 * 1024 * 2;      // 0.10 MB
    u16*   WdtNB = (u16*)(ws + off); off += (size_t)16 * 1024 * 2;      // 0.03 MB
    u16*   WoutT = (u16*)(ws + off); off += (size_t)512 * 1024 * 2;     // 1.0 MB
    // scratch union: xbf (18.9 MB) dead before Qbuf (bf16, 33.55 MB) written
    char*  scr   = ws + off; off += (size_t)NBATCH * NCH * DINNER * DSTATE * 2; // 33.55 MB
    u16*   xbf   = (u16*)scr;
    u16*   Qbuf  = (u16*)scr;

    k_prep<<<9216 + 6400, 256, 0, stream>>>(x, W_in, W_out, W_xproj, W_dtN,
                                            xbf, WinT, WoutT, WxpB, WdtNB);
    k_gemm_mfma<512, 512, 512, 2048, false>
        <<<dim3(2048 / 128, NROWS / 128), 256, 0, stream>>>(xbf, WinT, nullptr, xz);
    k_conv<<<NBATCH * (HEIGHT / 2) * (WIDTH / 8), 256, 0, stream>>>(xz, conv_k, xc);
    k_xproj<<<NROWS / 64, 256, 0, stream>>>(xc, WxpB, xpb);
    k_dt<<<(NROWS * DINNER / 8) / 256, 256, 0, stream>>>(xpb, W_dt, b_dt, dtb);
    k_dtn<<<NROWS / 64, 256, 0, stream>>>(dtb, WdtNB, b_dtN, xpb, dnBC);
    k_scan_p1<<<NBATCH * NCH * 4, 256, 0, stream>>>(xc, dtb, dnBC, A_log,
                                                    sdtb, Qbuf);
    k_scan_p2<<<(NBATCH * DINNER * DSTATE) / 256, 256, 0, stream>>>(sdtb, A_log, Qbuf);
    k_scan_p3<<<NBATCH * NCH * 4, 256, 0, stream>>>(xc, dtb, dnBC, A_log,
                                                    Dskip, Qbuf, xz);
    k_ln_gate<<<NROWS / 4, 256, 0, stream>>>(xz, ln_g, ln_b);
    k_gemm_mfma<1024, 2048, 1024, 512, true>
        <<<dim3(DMODEL / 128, NROWS / 128), 256, 0, stream>>>(xz, WoutT, b_out, out);
}

// Round 19
// 326.024 us; speedup vs baseline: 1.0284x; 1.0284x over previous
//
#include <hip/hip_runtime.h>
#include <hip/hip_bf16.h>

#define NBATCH 8
#define HEIGHT 48
#define WIDTH  48
#define DMODEL 512
#define DSTATE 16
#define DTRANK 8
#define DINNER 1024
#define LSEQ   (HEIGHT*WIDTH)     // 2304
#define NROWS  (NBATCH*LSEQ)      // 18432
#define NXP    40                 // DTRANK + 2*DSTATE
#define NCH    64                 // chunks per sequence
#define TCH    36                 // LSEQ / NCH

typedef unsigned short u16;
typedef unsigned int   u32;
typedef __attribute__((ext_vector_type(8))) short short8;
typedef __attribute__((ext_vector_type(4))) float f32x4;

__device__ __forceinline__ float bf2f(u16 u) {
    u32 x = ((u32)u) << 16;
    return __uint_as_float(x);
}
__device__ __forceinline__ u16 f2bf(float f) {
    u32 x = __float_as_uint(f);
    u32 r = (x + 0x7FFFu + ((x >> 16) & 1u)) >> 16;
    return (u16)r;
}

#if __has_builtin(__builtin_amdgcn_exp2f)
__device__ __forceinline__ float EXP2(float x) { return __builtin_amdgcn_exp2f(x); }
#else
__device__ __forceinline__ float EXP2(float x) { return __expf(x * 0.69314718f); }
#endif

#define GLD16(g, l) __builtin_amdgcn_global_load_lds( \
    (const __attribute__((address_space(1))) void*)(g), \
    (__attribute__((address_space(3))) void*)(l), 16, 0, 0)

// ---------------------------------------------------------------------------
// P0: merged prep: x (f32)->xbf (bf16), and the 4 weight preps.
// ---------------------------------------------------------------------------
__global__ __launch_bounds__(256) void k_prep(const float* __restrict__ x,
                                              const float* __restrict__ W_in,
                                              const float* __restrict__ W_out,
                                              const float* __restrict__ W_xproj,
                                              const float* __restrict__ W_dtN,
                                              u16* __restrict__ xbf,
                                              u16* __restrict__ WinT,
                                              u16* __restrict__ WoutT,
                                              u16* __restrict__ WxpB,
                                              u16* __restrict__ WdtNB) {
    if (blockIdx.x < 9216) {
        int i = blockIdx.x * 256 + threadIdx.x;
        float4 v = *reinterpret_cast<const float4*>(x + (size_t)i * 4);
        ushort4 o;
        o.x = f2bf(v.x); o.y = f2bf(v.y); o.z = f2bf(v.z); o.w = f2bf(v.w);
        *reinterpret_cast<ushort4*>(xbf + (size_t)i * 4) = o;
        return;
    }
    int idx = (blockIdx.x - 9216) * 256 + threadIdx.x;
    if (idx < 2048 * 512) {
        int n = idx >> 9, k = idx & 511;
        WinT[idx] = f2bf(W_in[(size_t)k * 2048 + n]);
    } else if (idx < 2048 * 512 + 512 * 1024) {
        int j = idx - 2048 * 512;
        int n = j >> 10, k = j & 1023;
        WoutT[j] = f2bf(W_out[(size_t)k * 512 + n]);
    } else if (idx < 2048 * 512 + 512 * 1024 + 48 * 1024) {
        int j = idx - (2048 * 512 + 512 * 1024);
        int n = j >> 10, k = j & 1023;
        WxpB[j] = (n < NXP) ? f2bf(W_xproj[(size_t)k * NXP + n]) : (u16)0;
    } else {
        int j = idx - (2048 * 512 + 512 * 1024 + 48 * 1024);
        int n = j >> 10, k = j & 1023;
        WdtNB[j] = f2bf(W_dtN[(size_t)k * DSTATE + n]);
    }
}

// ---------------------------------------------------------------------------
// K1/K6: bf16 MFMA GEMM, 128x128 tile, BK=32, 4 waves (2x2), 4x4 fragments.
// XCD-aware block swizzle.
// ---------------------------------------------------------------------------
template<int K, int LDA, int LDB, int LDC, bool F32OUT>
__global__ __launch_bounds__(256) void k_gemm_mfma(const u16* __restrict__ A,
                                                   const u16* __restrict__ B,
                                                   const float* __restrict__ bias,
                                                   void* __restrict__ Cv) {
    __shared__ u16 As[128 * 32];
    __shared__ u16 Bs[128 * 32];
    const int tid = threadIdx.x;
    const int l   = tid & 63;
    const int w   = tid >> 6;
    const int wm  = w >> 1, wn = w & 1;
    const int id   = blockIdx.y * gridDim.x + blockIdx.x;
    const int nwg  = gridDim.x * gridDim.y;
    const int swz  = (id & 7) * (nwg >> 3) + (id >> 3);
    const int bx   = swz % gridDim.x;
    const int by   = swz / gridDim.x;
    const int m0  = by * 128, n0 = bx * 128;
    const int srow = w * 32 + (l >> 2);
    const int sc   = l & 3;
    const int kh = l >> 4;
    const int lr = l & 15;

    f32x4 acc[4][4];
#pragma unroll
    for (int i = 0; i < 4; ++i)
#pragma unroll
        for (int j = 0; j < 4; ++j)
            acc[i][j] = (f32x4){0.f, 0.f, 0.f, 0.f};

    for (int k0 = 0; k0 < K; k0 += 32) {
#pragma unroll
        for (int i = 0; i < 2; ++i) {
            int r  = srow + i * 16;
            int cg = sc ^ ((r >> 1) & 3);
            const u16* ga = A + (size_t)(m0 + r) * LDA + k0 + cg * 8;
            const u16* gb = B + (size_t)(n0 + r) * LDB + k0 + cg * 8;
            GLD16(ga, As + (w * 2 + i) * 512);
            GLD16(gb, Bs + (w * 2 + i) * 512);
        }
        __syncthreads();
        short8 af[4], bfr[4];
#pragma unroll
        for (int f = 0; f < 4; ++f) {
            int ar = wm * 64 + f * 16 + lr;
            af[f]  = *reinterpret_cast<const short8*>(As + ar * 32 + ((kh ^ ((ar >> 1) & 3)) * 8));
            int br = wn * 64 + f * 16 + lr;
            bfr[f] = *reinterpret_cast<const short8*>(Bs + br * 32 + ((kh ^ ((br >> 1) & 3)) * 8));
        }
#pragma unroll
        for (int fm = 0; fm < 4; ++fm)
#pragma unroll
            for (int fn = 0; fn < 4; ++fn)
                acc[fm][fn] = __builtin_amdgcn_mfma_f32_16x16x32_bf16(
                    af[fm], bfr[fn], acc[fm][fn], 0, 0, 0);
        __syncthreads();
    }

#pragma unroll
    for (int fm = 0; fm < 4; ++fm) {
#pragma unroll
        for (int r = 0; r < 4; ++r) {
            int row = m0 + wm * 64 + fm * 16 + (l >> 4) * 4 + r;
#pragma unroll
            for (int fn = 0; fn < 4; ++fn) {
                int col = n0 + wn * 64 + fn * 16 + lr;
                if (F32OUT) {
                    ((float*)Cv)[(size_t)row * LDC + col] = acc[fm][fn][r] + bias[col];
                } else {
                    ((u16*)Cv)[(size_t)row * LDC + col] = f2bf(acc[fm][fn][r]);
                }
            }
        }
    }
}

// ---------------------------------------------------------------------------
// K2: depthwise 3x3 SAME conv, 2h x 8w blocking.
// ---------------------------------------------------------------------------
__global__ __launch_bounds__(256) void k_conv(const u16* __restrict__ xz,
                                              const float* __restrict__ ck,
                                              u16* __restrict__ xc) {
    const int blk = blockIdx.x;
    const int wg = blk % (WIDTH / 8);
    const int rest = blk / (WIDTH / 8);
    const int hp = rest % (HEIGHT / 2);
    const int b = rest / (HEIGHT / 2);
    const int h0 = hp * 2;
    const int w0 = wg * 8;
    const int c0 = threadIdx.x * 4;

    float acc[16][4];
#pragma unroll
    for (int j = 0; j < 16; ++j)
#pragma unroll
        for (int q = 0; q < 4; ++q) acc[j][q] = 0.f;

#pragma unroll
    for (int i = 0; i < 4; ++i) {
        int hh = h0 - 1 + i;
        if (hh < 0 || hh >= HEIGHT) continue;
        const u16* rp = xz + ((size_t)(b * HEIGHT + hh) * WIDTH) * 2048 + c0;
        float a[10][4];
#pragma unroll
        for (int p = 0; p < 10; ++p) {
            int ww = w0 - 1 + p;
            if (ww >= 0 && ww < WIDTH) {
                ushort4 v = *reinterpret_cast<const ushort4*>(rp + (size_t)ww * 2048);
                a[p][0] = bf2f(v.x); a[p][1] = bf2f(v.y);
                a[p][2] = bf2f(v.z); a[p][3] = bf2f(v.w);
            } else {
                a[p][0] = a[p][1] = a[p][2] = a[p][3] = 0.f;
            }
        }
#pragma unroll
        for (int oh = 0; oh < 2; ++oh) {
            int kh = i - oh;
            if (kh < 0 || kh > 2) continue;
#pragma unroll
            for (int kw = 0; kw < 3; ++kw) {
                float4 kv = *reinterpret_cast<const float4*>(ck + (kh * 3 + kw) * DINNER + c0);
#pragma unroll
                for (int j = 0; j < 8; ++j) {
                    acc[oh * 8 + j][0] = fmaf(a[j + kw][0], kv.x, acc[oh * 8 + j][0]);
                    acc[oh * 8 + j][1] = fmaf(a[j + kw][1], kv.y, acc[oh * 8 + j][1]);
                    acc[oh * 8 + j][2] = fmaf(a[j + kw][2], kv.z, acc[oh * 8 + j][2]);
                    acc[oh * 8 + j][3] = fmaf(a[j + kw][3], kv.w, acc[oh * 8 + j][3]);
                }
            }
        }
    }
#pragma unroll
    for (int oh = 0; oh < 2; ++oh) {
        const size_t orow = (size_t)((b * HEIGHT + h0 + oh) * WIDTH + w0);
#pragma unroll
        for (int j = 0; j < 8; ++j) {
            ushort4 ov;
            ov.x = f2bf(acc[oh * 8 + j][0]); ov.y = f2bf(acc[oh * 8 + j][1]);
            ov.z = f2bf(acc[oh * 8 + j][2]); ov.w = f2bf(acc[oh * 8 + j][3]);
            *reinterpret_cast<ushort4*>(xc + (orow + j) * DINNER + c0) = ov;
        }
    }
}

// ---------------------------------------------------------------------------
// K3a: xp = xc @ WxpB^T via MFMA. M-tile=64, N=48, K=1024.
// ---------------------------------------------------------------------------
__global__ __launch_bounds__(256) void k_xproj(const u16* __restrict__ xc,
                                               const u16* __restrict__ WxpB,
                                               float* __restrict__ xp_out) {
    __shared__ u16 As[64 * 32];
    __shared__ u16 Bs[48 * 32];
    const int tid = threadIdx.x;
    const int l = tid & 63;
    const int w = tid >> 6;
    const int m0 = blockIdx.x * 64;
    const int kh = l >> 4, lr = l & 15;
    const int srow = w * 16 + (l >> 2);
    const int sc = l & 3;

    f32x4 acc[3];
    acc[0] = acc[1] = acc[2] = (f32x4){0.f, 0.f, 0.f, 0.f};

    for (int k0 = 0; k0 < 1024; k0 += 32) {
        {
            int cg = sc ^ ((srow >> 1) & 3);
            GLD16(xc + (size_t)(m0 + srow) * DINNER + k0 + cg * 8, As + w * 512);
            if (w < 3)
                GLD16(WxpB + (size_t)srow * 1024 + k0 + cg * 8, Bs + w * 512);
        }
        __syncthreads();
        int ar = w * 16 + lr;
        short8 af = *reinterpret_cast<const short8*>(As + ar * 32 + ((kh ^ ((ar >> 1) & 3)) * 8));
#pragma unroll
        for (int fn = 0; fn < 3; ++fn) {
            int br = fn * 16 + lr;
            short8 bf = *reinterpret_cast<const short8*>(Bs + br * 32 + ((kh ^ ((br >> 1) & 3)) * 8));
            acc[fn] = __builtin_amdgcn_mfma_f32_16x16x32_bf16(af, bf, acc[fn], 0, 0, 0);
        }
        __syncthreads();
    }
#pragma unroll
    for (int fn = 0; fn < 3; ++fn)
#pragma unroll
        for (int r = 0; r < 4; ++r) {
            int row = m0 + w * 16 + (l >> 4) * 4 + r;
            int col = fn * 16 + lr;
            if (col < NXP) xp_out[(size_t)row * NXP + col] = acc[fn][r];
        }
}

// ---------------------------------------------------------------------------
// K3b: dt = softplus(xp[:, :8] @ W_dt + b_dt) -> bf16 [row][1024]
// ---------------------------------------------------------------------------
__global__ __launch_bounds__(256) void k_dt(const float* __restrict__ xp,
                                            const float* __restrict__ W_dt,
                                            const float* __restrict__ b_dt,
                                            u16* __restrict__ dt_out) {
    int gid = blockIdx.x * 256 + threadIdx.x;
    int row = gid >> 7;
    int dj  = (gid & 127) * 8;
    const float* xr = xp + (size_t)row * NXP;
    float4 xa = *reinterpret_cast<const float4*>(xr);
    float4 xb = *reinterpret_cast<const float4*>(xr + 4);
    float xv[8] = {xa.x, xa.y, xa.z, xa.w, xb.x, xb.y, xb.z, xb.w};
    float a[8];
    {
        float4 b0 = *reinterpret_cast<const float4*>(b_dt + dj);
        float4 b1 = *reinterpret_cast<const float4*>(b_dt + dj + 4);
        a[0]=b0.x; a[1]=b0.y; a[2]=b0.z; a[3]=b0.w;
        a[4]=b1.x; a[5]=b1.y; a[6]=b1.z; a[7]=b1.w;
    }
#pragma unroll
    for (int j = 0; j < 8; ++j) {
        float4 w0 = *reinterpret_cast<const float4*>(W_dt + j * DINNER + dj);
        float4 w1 = *reinterpret_cast<const float4*>(W_dt + j * DINNER + dj + 4);
        a[0] = fmaf(xv[j], w0.x, a[0]); a[1] = fmaf(xv[j], w0.y, a[1]);
        a[2] = fmaf(xv[j], w0.z, a[2]); a[3] = fmaf(xv[j], w0.w, a[3]);
        a[4] = fmaf(xv[j], w1.x, a[4]); a[5] = fmaf(xv[j], w1.y, a[5]);
        a[6] = fmaf(xv[j], w1.z, a[6]); a[7] = fmaf(xv[j], w1.w, a[7]);
    }
    short8 o;
#pragma unroll
    for (int j = 0; j < 8; ++j) {
        float dt = fmaxf(a[j], 0.f) + log1pf(__expf(-fabsf(a[j])));
        o[j] = (short)f2bf(dt);
    }
    *reinterpret_cast<short8*>(dt_out + (size_t)row * DINNER + dj) = o;
}

// ---------------------------------------------------------------------------
// K3c: dtN = dt @ WdtNB^T + b_dtN via MFMA (M-tile=64, N=16, K=1024), then
// fused epilogue writes dnBC[row][32] = { dtN*B , C } (f32).
// ---------------------------------------------------------------------------
__global__ __launch_bounds__(256) void k_dtn(const u16* __restrict__ dtb,
                                             const u16* __restrict__ WdtNB,
                                             const float* __restrict__ b_dtN,
                                             const float* __restrict__ xp,
                                             float* __restrict__ dnBC) {
    __shared__ u16 As[64 * 32];
    __shared__ u16 Bs[16 * 32];
    const int tid = threadIdx.x;
    const int l = tid & 63;
    const int w = tid >> 6;
    const int m0 = blockIdx.x * 64;
    const int kh = l >> 4, lr = l & 15;
    const int srow = w * 16 + (l >> 2);
    const int sc = l & 3;

    f32x4 acc = (f32x4){0.f, 0.f, 0.f, 0.f};

    for (int k0 = 0; k0 < 1024; k0 += 32) {
        {
            int cg = sc ^ ((srow >> 1) & 3);
            GLD16(dtb + (size_t)(m0 + srow) * DINNER + k0 + cg * 8, As + w * 512);
            if (w == 0)
                GLD16(WdtNB + (size_t)srow * 1024 + k0 + cg * 8, Bs);
        }
        __syncthreads();
        int ar = w * 16 + lr;
        short8 af = *reinterpret_cast<const short8*>(As + ar * 32 + ((kh ^ ((ar >> 1) & 3)) * 8));
        short8 bf = *reinterpret_cast<const short8*>(Bs + lr * 32 + ((kh ^ ((lr >> 1) & 3)) * 8));
        acc = __builtin_amdgcn_mfma_f32_16x16x32_bf16(af, bf, acc, 0, 0, 0);
        __syncthreads();
    }
    float bn = b_dtN[lr];
#pragma unroll
    for (int r = 0; r < 4; ++r) {
        int row = m0 + w * 16 + (l >> 4) * 4 + r;
        float dn = acc[r] + bn;
        float Bv = xp[(size_t)row * NXP + DTRANK + lr];
        float Cv = xp[(size_t)row * NXP + DTRANK + DSTATE + lr];
        dnBC[(size_t)row * 32 + lr]      = dn * Bv;
        dnBC[(size_t)row * 32 + 16 + lr] = Cv;
    }
}

// ---------------------------------------------------------------------------
// K4a: chunk-local scan; lane = d, 16 states in registers; A/B-rotated
// 1-iteration register prefetch of dt/xc. Q stored bf16.
// ---------------------------------------------------------------------------
#define P1_N(IDX, COMP) \
    dA = EXP2(dt * An2[IDX]); h[IDX] = fmaf(dA, h[IDX], COMP * xt);

#define P1_BODY(T, DTC, XCC, DTN, XCN, PR) { \
    const float4* sv = pS + (size_t)(T) * 8; \
    float4 u0 = sv[0], u1 = sv[1], u2 = sv[2], u3 = sv[3]; \
    if (PR) { DTN = pdt[(size_t)((T) + 1) * DINNER]; \
              XCN = pxc[(size_t)((T) + 1) * DINNER]; } \
    float dt = bf2f(DTC), xt = bf2f(XCC); \
    sdt += dt; \
    float dA; \
    P1_N(0,  u0.x) P1_N(1,  u0.y) P1_N(2,  u0.z) P1_N(3,  u0.w) \
    P1_N(4,  u1.x) P1_N(5,  u1.y) P1_N(6,  u1.z) P1_N(7,  u1.w) \
    P1_N(8,  u2.x) P1_N(9,  u2.y) P1_N(10, u2.z) P1_N(11, u2.w) \
    P1_N(12, u3.x) P1_N(13, u3.y) P1_N(14, u3.z) P1_N(15, u3.w) }

__global__ __launch_bounds__(256) void k_scan_p1(const u16* __restrict__ xc,
                                                 const u16* __restrict__ dtb,
                                                 const float* __restrict__ dnBC,
                                                 const float* __restrict__ A_log,
                                                 float* __restrict__ sdt_out,
                                                 u16* __restrict__ Qbuf) {
    const int tid = threadIdx.x;
    const int id  = blockIdx.x;
    const int swz = (id & 7) * ((NBATCH * NCH * 4) >> 3) + (id >> 3);
    const int quarter = swz & 3;
    const int bc = swz >> 2;            // b*NCH + c
    const int c = bc & (NCH - 1);
    const int b = bc >> 6;
    const int d = quarter * 256 + tid;

    float An2[16];
#pragma unroll
    for (int n = 0; n < 16; ++n)
        An2[n] = -__expf(A_log[n]) * 1.44269504f;   // A_n * log2(e)

    float h[16];
#pragma unroll
    for (int n = 0; n < 16; ++n) h[n] = 0.f;
    float sdt = 0.f;

    const size_t row0 = (size_t)b * LSEQ + (size_t)c * TCH;
    const u16* pdt = dtb + row0 * DINNER + d;
    const u16* pxc = xc  + row0 * DINNER + d;
    const float4* pS = reinterpret_cast<const float4*>(dnBC + row0 * 32);

    u16 dtA = pdt[0], xcA = pxc[0];
    u16 dtB, xcB;

    for (int t = 0; t < TCH - 2; t += 2) {
        P1_BODY(t,     dtA, xcA, dtB, xcB, true)
        P1_BODY(t + 1, dtB, xcB, dtA, xcA, true)
    }
    P1_BODY(TCH - 2, dtA, xcA, dtB, xcB, true)
    P1_BODY(TCH - 1, dtB, xcB, dtA, xcA, false)

    sdt_out[(size_t)bc * DINNER + d] = sdt;
    size_t base = ((size_t)bc << 14) + d;   // [bc][n][d]
#pragma unroll
    for (int n = 0; n < 16; ++n)
        Qbuf[base + (size_t)n * DINNER] = f2bf(h[n]);
}

// ---------------------------------------------------------------------------
// K4b: combine chunk states. thread = (b, n, d); NCH sequential steps.
// P recomputed from sdt; Q in bf16 (combine itself in f32).
// ---------------------------------------------------------------------------
__global__ __launch_bounds__(256) void k_scan_p2(const float* __restrict__ sdt,
                                                 const float* __restrict__ A_log,
                                                 u16* __restrict__ Qbuf) {
    int tid = blockIdx.x * 256 + threadIdx.x;
    int b = tid >> 14, rem = tid & 16383;
    int n = rem >> 10, d = rem & 1023;
    float An2 = -__expf(A_log[n]) * 1.44269504f;
    float h = 0.f;
    for (int c = 0; c < NCH; ++c) {
        int bc = b * NCH + c;
        float P = EXP2(sdt[(size_t)bc * DINNER + d] * An2);
        size_t idx = ((size_t)bc << 14) + rem;
        float q = bf2f(Qbuf[idx]);
        Qbuf[idx] = f2bf(h);           // h_start for chunk c
        h = fmaf(P, h, q);
    }
}

// ---------------------------------------------------------------------------
// K4c: re-run chunk from true h_start; A/B-rotated register prefetch;
// y = C·h + D*x written to xz y-half. Q in bf16.
// ---------------------------------------------------------------------------
#define P3_N(IDX, UC, CC, YS) \
    dA = EXP2(dt * An2[IDX]); h[IDX] = fmaf(dA, h[IDX], UC * xt); \
    YS = fmaf(h[IDX], CC, YS);

#define P3_BODY(T, DTC, XCC, DTN, XCN, PR) { \
    const float4* sv = pS + (size_t)(T) * 8; \
    float4 u0 = sv[0], u1 = sv[1], u2 = sv[2], u3 = sv[3]; \
    float4 c4 = sv[4], c5 = sv[5], c6 = sv[6], c7 = sv[7]; \
    if (PR) { DTN = pdt[(size_t)((T) + 1) * DINNER]; \
              XCN = pxc[(size_t)((T) + 1) * DINNER]; } \
    float dt = bf2f(DTC), xt = bf2f(XCC); \
    float ys0 = Dsk * xt, ys1 = 0.f, ys2 = 0.f, ys3 = 0.f; \
    float dA; \
    P3_N(0,  u0.x, c4.x, ys0) P3_N(1,  u0.y, c4.y, ys1) \
    P3_N(2,  u0.z, c4.z, ys2) P3_N(3,  u0.w, c4.w, ys3) \
    P3_N(4,  u1.x, c5.x, ys0) P3_N(5,  u1.y, c5.y, ys1) \
    P3_N(6,  u1.z, c5.z, ys2) P3_N(7,  u1.w, c5.w, ys3) \
    P3_N(8,  u2.x, c6.x, ys0) P3_N(9,  u2.y, c6.y, ys1) \
    P3_N(10, u2.z, c6.z, ys2) P3_N(11, u2.w, c6.w, ys3) \
    P3_N(12, u3.x, c7.x, ys0) P3_N(13, u3.y, c7.y, ys1) \
    P3_N(14, u3.z, c7.z, ys2) P3_N(15, u3.w, c7.w, ys3) \
    ybuf[(row0 + (T)) * 2048 + d] = f2bf((ys0 + ys1) + (ys2 + ys3)); }

__global__ __launch_bounds__(256) void k_scan_p3(const u16* __restrict__ xc,
                                                 const u16* __restrict__ dtb,
                                                 const float* __restrict__ dnBC,
                                                 const float* __restrict__ A_log,
                                                 const float* __restrict__ Dskip,
                                                 const u16* __restrict__ Qbuf,
                                                 u16* __restrict__ ybuf) {
    const int tid = threadIdx.x;
    const int id  = blockIdx.x;
    const int swz = (id & 7) * ((NBATCH * NCH * 4) >> 3) + (id >> 3);
    const int quarter = swz & 3;
    const int bc = swz >> 2;
    const int c = bc & (NCH - 1);
    const int b = bc >> 6;
    const int d = quarter * 256 + tid;

    float An2[16];
#pragma unroll
    for (int n = 0; n < 16; ++n)
        An2[n] = -__expf(A_log[n]) * 1.44269504f;

    float h[16];
    size_t base = ((size_t)bc << 14) + d;   // [bc][n][d]
#pragma unroll
    for (int n = 0; n < 16; ++n) h[n] = bf2f(Qbuf[base + (size_t)n * DINNER]);
    float Dsk = Dskip[d];

    const size_t row0 = (size_t)b * LSEQ + (size_t)c * TCH;
    const u16* pdt = dtb + row0 * DINNER + d;
    const u16* pxc = xc  + row0 * DINNER + d;
    const float4* pS = reinterpret_cast<const float4*>(dnBC + row0 * 32);

    u16 dtA = pdt[0], xcA = pxc[0];
    u16 dtB, xcB;

    for (int t = 0; t < TCH - 2; t += 2) {
        P3_BODY(t,     dtA, xcA, dtB, xcB, true)
        P3_BODY(t + 1, dtB, xcB, dtA, xcA, true)
    }
    P3_BODY(TCH - 2, dtA, xcA, dtB, xcB, true)
    P3_BODY(TCH - 1, dtB, xcB, dtA, xcA, false)
}

// ---------------------------------------------------------------------------
// K5: LayerNorm(y) * ln_g + ln_b, then * silu(z). Wave-per-row (no LDS,
// no barrier): 4608 blocks x 4 waves; lane owns 16 contiguous channels.
// ---------------------------------------------------------------------------
__global__ __launch_bounds__(256) void k_ln_gate(u16* __restrict__ xz,
                                                 const float* __restrict__ ln_g,
                                                 const float* __restrict__ ln_b) {
    const int wv = threadIdx.x >> 6, l = threadIdx.x & 63;
    const int row = blockIdx.x * 4 + wv;
    u16* yrow = xz + (size_t)row * 2048;
    const int c0 = l * 16;

    short8 v0 = *reinterpret_cast<const short8*>(yrow + c0);
    short8 v1 = *reinterpret_cast<const short8*>(yrow + c0 + 8);
    float y[16];
#pragma unroll
    for (int j = 0; j < 8; ++j) {
        y[j]     = bf2f((u16)v0[j]);
        y[8 + j] = bf2f((u16)v1[j]);
    }
    float s = 0.f, q = 0.f;
#pragma unroll
    for (int j = 0; j < 16; ++j) { s += y[j]; q = fmaf(y[j], y[j], q); }
#pragma unroll
    for (int m = 32; m; m >>= 1) {
        s += __shfl_xor(s, m, 64);
        q += __shfl_xor(q, m, 64);
    }
    float mu = s * (1.f / DINNER);
    float var = q * (1.f / DINNER) - mu * mu;
    float rstd = rsqrtf(var + 1e-5f);

    short8 z0 = *reinterpret_cast<const short8*>(yrow + DINNER + c0);
    short8 z1 = *reinterpret_cast<const short8*>(yrow + DINNER + c0 + 8);
    float4 lg0 = *reinterpret_cast<const float4*>(ln_g + c0);
    float4 lg1 = *reinterpret_cast<const float4*>(ln_g + c0 + 4);
    float4 lg2 = *reinterpret_cast<const float4*>(ln_g + c0 + 8);
    float4 lg3 = *reinterpret_cast<const float4*>(ln_g + c0 + 12);
    float4 lb0 = *reinterpret_cast<const float4*>(ln_b + c0);
    float4 lb1 = *reinterpret_cast<const float4*>(ln_b + c0 + 4);
    float4 lb2 = *reinterpret_cast<const float4*>(ln_b + c0 + 8);
    float4 lb3 = *reinterpret_cast<const float4*>(ln_b + c0 + 12);
    float lg[16] = {lg0.x,lg0.y,lg0.z,lg0.w, lg1.x,lg1.y,lg1.z,lg1.w,
                    lg2.x,lg2.y,lg2.z,lg2.w, lg3.x,lg3.y,lg3.z,lg3.w};
    float lb[16] = {lb0.x,lb0.y,lb0.z,lb0.w, lb1.x,lb1.y,lb1.z,lb1.w,
                    lb2.x,lb2.y,lb2.z,lb2.w, lb3.x,lb3.y,lb3.z,lb3.w};

    short8 o0, o1;
#pragma unroll
    for (int j = 0; j < 16; ++j) {
        float zv = bf2f((u16)((j < 8) ? z0[j] : z1[j - 8]));
        float g = ((y[j] - mu) * rstd * lg[j] + lb[j]) * (zv / (1.f + __expf(-zv)));
        if (j < 8) o0[j] = (short)f2bf(g); else o1[j - 8] = (short)f2bf(g);
    }
    *reinterpret_cast<short8*>(yrow + c0)     = o0;
    *reinterpret_cast<short8*>(yrow + c0 + 8) = o1;
}

// ---------------------------------------------------------------------------
extern "C" void kernel_launch(void* const* d_in, const int* in_sizes, int n_in,
                              void* d_out, int out_size, void* d_ws, size_t ws_size,
                              hipStream_t stream) {
    const float* x       = (const float*)d_in[0];
    const float* W_in    = (const float*)d_in[1];
    const float* conv_k  = (const float*)d_in[2];
    const float* W_xproj = (const float*)d_in[3];
    const float* W_dt    = (const float*)d_in[4];
    const float* b_dt    = (const float*)d_in[5];
    const float* A_log   = (const float*)d_in[6];
    const float* Dskip   = (const float*)d_in[7];
    const float* W_dtN   = (const float*)d_in[8];
    const float* b_dtN   = (const float*)d_in[9];
    const float* ln_g    = (const float*)d_in[10];
    const float* ln_b    = (const float*)d_in[11];
    const float* W_out   = (const float*)d_in[12];
    const float* b_out   = (const float*)d_in[13];
    float* out = (float*)d_out;

    char* ws = (char*)d_ws;
    size_t off = 0;
    u16*   xz    = (u16*)(ws + off); off += (size_t)NROWS * 2048 * 2;   // 75.5 MB
    u16*   xc    = (u16*)(ws + off); off += (size_t)NROWS * 1024 * 2;   // 37.7 MB
    u16*   dtb   = (u16*)(ws + off); off += (size_t)NROWS * 1024 * 2;   // 37.7 MB
    float* xpb   = (float*)(ws + off); off += (size_t)NROWS * NXP * 4;  // 2.95 MB
    float* dnBC  = (float*)(ws + off); off += (size_t)NROWS * 32 * 4;   // 2.36 MB
    // scratch union: xbf (18.9 MB) dead before Qbuf (bf16, 16.8 MB) written
    char*  scr   = ws + off; off += (size_t)NROWS * DMODEL * 2;         // 18.9 MB
    u16*   xbf   = (u16*)scr;
    u16*   Qbuf  = (u16*)scr;
    // sdt (2 MB) overlays xpb: xp is dead after k_dtn (scan consumes dnBC only)
    float* sdtb  = xpb;
    u16*   WinT  = (u16*)(ws + off); off += (size_t)2048 * 512 * 2;
    u16*   WoutT = (u16*)(ws + off); off += (size_t)512 * 1024 * 2;
    u16*   WxpB  = (u16*)(ws + off); off += (size_t)48 * 1024 * 2;
    u16*   WdtNB = (u16*)(ws + off); off += (size_t)16 * 1024 * 2;

    k_prep<<<9216 + 6400, 256, 0, stream>>>(x, W_in, W_out, W_xproj, W_dtN,
                                            xbf, WinT, WoutT, WxpB, WdtNB);
    k_gemm_mfma<512, 512, 512, 2048, false>
        <<<dim3(2048 / 128, NROWS / 128), 256, 0, stream>>>(xbf, WinT, nullptr, xz);
    k_conv<<<NBATCH * (HEIGHT / 2) * (WIDTH / 8), 256, 0, stream>>>(xz, conv_k, xc);
    k_xproj<<<NROWS / 64, 256, 0, stream>>>(xc, WxpB, xpb);
    k_dt<<<(NROWS * DINNER / 8) / 256, 256, 0, stream>>>(xpb, W_dt, b_dt, dtb);
    k_dtn<<<NROWS / 64, 256, 0, stream>>>(dtb, WdtNB, b_dtN, xpb, dnBC);
    k_scan_p1<<<NBATCH * NCH * 4, 256, 0, stream>>>(xc, dtb, dnBC, A_log,
                                                    sdtb, Qbuf);
    k_scan_p2<<<(NBATCH * DINNER * DSTATE) / 256, 256, 0, stream>>>(sdtb, A_log, Qbuf);
    k_scan_p3<<<NBATCH * NCH * 4, 256, 0, stream>>>(xc, dtb, dnBC, A_log,
                                                    Dskip, Qbuf, xz);
    k_ln_gate<<<NROWS / 4, 256, 0, stream>>>(xz, ln_g, ln_b);
    k_gemm_mfma<1024, 2048, 1024, 512, true>
        <<<dim3(DMODEL / 128, NROWS / 128), 256, 0, stream>>>(xz, WoutT, b_out, out);
}

// Round 20
// 323.792 us; speedup vs baseline: 1.0355x; 1.0069x over previous
//
#include <hip/hip_runtime.h>
#include <hip/hip_bf16.h>

#define NBATCH 8
#define HEIGHT 48
#define WIDTH  48
#define DMODEL 512
#define DSTATE 16
#define DTRANK 8
#define DINNER 1024
#define LSEQ   (HEIGHT*WIDTH)     // 2304
#define NROWS  (NBATCH*LSEQ)      // 18432
#define NXP    40                 // DTRANK + 2*DSTATE
#define NCH    64                 // chunks per sequence
#define TCH    36                 // LSEQ / NCH

typedef unsigned short u16;
typedef unsigned int   u32;
typedef __attribute__((ext_vector_type(8))) short short8;
typedef __attribute__((ext_vector_type(4))) float f32x4;
typedef __attribute__((ext_vector_type(2))) float f32x2;

__device__ __forceinline__ float bf2f(u16 u) {
    u32 x = ((u32)u) << 16;
    return __uint_as_float(x);
}
__device__ __forceinline__ u16 f2bf(float f) {
    u32 x = __float_as_uint(f);
    u32 r = (x + 0x7FFFu + ((x >> 16) & 1u)) >> 16;
    return (u16)r;
}

#if __has_builtin(__builtin_amdgcn_exp2f)
__device__ __forceinline__ float EXP2(float x) { return __builtin_amdgcn_exp2f(x); }
#else
__device__ __forceinline__ float EXP2(float x) { return __expf(x * 0.69314718f); }
#endif

#define GLD16(g, l) __builtin_amdgcn_global_load_lds( \
    (const __attribute__((address_space(1))) void*)(g), \
    (__attribute__((address_space(3))) void*)(l), 16, 0, 0)

// ---------------------------------------------------------------------------
// P0: merged prep: x (f32)->xbf (bf16), and the 4 weight preps.
// ---------------------------------------------------------------------------
__global__ __launch_bounds__(256) void k_prep(const float* __restrict__ x,
                                              const float* __restrict__ W_in,
                                              const float* __restrict__ W_out,
                                              const float* __restrict__ W_xproj,
                                              const float* __restrict__ W_dtN,
                                              u16* __restrict__ xbf,
                                              u16* __restrict__ WinT,
                                              u16* __restrict__ WoutT,
                                              u16* __restrict__ WxpB,
                                              u16* __restrict__ WdtNB) {
    if (blockIdx.x < 9216) {
        int i = blockIdx.x * 256 + threadIdx.x;
        float4 v = *reinterpret_cast<const float4*>(x + (size_t)i * 4);
        ushort4 o;
        o.x = f2bf(v.x); o.y = f2bf(v.y); o.z = f2bf(v.z); o.w = f2bf(v.w);
        *reinterpret_cast<ushort4*>(xbf + (size_t)i * 4) = o;
        return;
    }
    int idx = (blockIdx.x - 9216) * 256 + threadIdx.x;
    if (idx < 2048 * 512) {
        int n = idx >> 9, k = idx & 511;
        WinT[idx] = f2bf(W_in[(size_t)k * 2048 + n]);
    } else if (idx < 2048 * 512 + 512 * 1024) {
        int j = idx - 2048 * 512;
        int n = j >> 10, k = j & 1023;
        WoutT[j] = f2bf(W_out[(size_t)k * 512 + n]);
    } else if (idx < 2048 * 512 + 512 * 1024 + 48 * 1024) {
        int j = idx - (2048 * 512 + 512 * 1024);
        int n = j >> 10, k = j & 1023;
        WxpB[j] = (n < NXP) ? f2bf(W_xproj[(size_t)k * NXP + n]) : (u16)0;
    } else {
        int j = idx - (2048 * 512 + 512 * 1024 + 48 * 1024);
        int n = j >> 10, k = j & 1023;
        WdtNB[j] = f2bf(W_dtN[(size_t)k * DSTATE + n]);
    }
}

// ---------------------------------------------------------------------------
// K1/K6: bf16 MFMA GEMM, 128x128 tile, BK=32, 4 waves (2x2), 4x4 fragments.
// XCD-aware block swizzle.
// ---------------------------------------------------------------------------
template<int K, int LDA, int LDB, int LDC, bool F32OUT>
__global__ __launch_bounds__(256) void k_gemm_mfma(const u16* __restrict__ A,
                                                   const u16* __restrict__ B,
                                                   const float* __restrict__ bias,
                                                   void* __restrict__ Cv) {
    __shared__ u16 As[128 * 32];
    __shared__ u16 Bs[128 * 32];
    const int tid = threadIdx.x;
    const int l   = tid & 63;
    const int w   = tid >> 6;
    const int wm  = w >> 1, wn = w & 1;
    const int id   = blockIdx.y * gridDim.x + blockIdx.x;
    const int nwg  = gridDim.x * gridDim.y;
    const int swz  = (id & 7) * (nwg >> 3) + (id >> 3);
    const int bx   = swz % gridDim.x;
    const int by   = swz / gridDim.x;
    const int m0  = by * 128, n0 = bx * 128;
    const int srow = w * 32 + (l >> 2);
    const int sc   = l & 3;
    const int kh = l >> 4;
    const int lr = l & 15;

    f32x4 acc[4][4];
#pragma unroll
    for (int i = 0; i < 4; ++i)
#pragma unroll
        for (int j = 0; j < 4; ++j)
            acc[i][j] = (f32x4){0.f, 0.f, 0.f, 0.f};

    for (int k0 = 0; k0 < K; k0 += 32) {
#pragma unroll
        for (int i = 0; i < 2; ++i) {
            int r  = srow + i * 16;
            int cg = sc ^ ((r >> 1) & 3);
            const u16* ga = A + (size_t)(m0 + r) * LDA + k0 + cg * 8;
            const u16* gb = B + (size_t)(n0 + r) * LDB + k0 + cg * 8;
            GLD16(ga, As + (w * 2 + i) * 512);
            GLD16(gb, Bs + (w * 2 + i) * 512);
        }
        __syncthreads();
        short8 af[4], bfr[4];
#pragma unroll
        for (int f = 0; f < 4; ++f) {
            int ar = wm * 64 + f * 16 + lr;
            af[f]  = *reinterpret_cast<const short8*>(As + ar * 32 + ((kh ^ ((ar >> 1) & 3)) * 8));
            int br = wn * 64 + f * 16 + lr;
            bfr[f] = *reinterpret_cast<const short8*>(Bs + br * 32 + ((kh ^ ((br >> 1) & 3)) * 8));
        }
#pragma unroll
        for (int fm = 0; fm < 4; ++fm)
#pragma unroll
            for (int fn = 0; fn < 4; ++fn)
                acc[fm][fn] = __builtin_amdgcn_mfma_f32_16x16x32_bf16(
                    af[fm], bfr[fn], acc[fm][fn], 0, 0, 0);
        __syncthreads();
    }

#pragma unroll
    for (int fm = 0; fm < 4; ++fm) {
#pragma unroll
        for (int r = 0; r < 4; ++r) {
            int row = m0 + wm * 64 + fm * 16 + (l >> 4) * 4 + r;
#pragma unroll
            for (int fn = 0; fn < 4; ++fn) {
                int col = n0 + wn * 64 + fn * 16 + lr;
                if (F32OUT) {
                    ((float*)Cv)[(size_t)row * LDC + col] = acc[fm][fn][r] + bias[col];
                } else {
                    ((u16*)Cv)[(size_t)row * LDC + col] = f2bf(acc[fm][fn][r]);
                }
            }
        }
    }
}

// ---------------------------------------------------------------------------
// K2: depthwise 3x3 SAME conv, 2h x 8w blocking.
// ---------------------------------------------------------------------------
__global__ __launch_bounds__(256) void k_conv(const u16* __restrict__ xz,
                                              const float* __restrict__ ck,
                                              u16* __restrict__ xc) {
    const int blk = blockIdx.x;
    const int wg = blk % (WIDTH / 8);
    const int rest = blk / (WIDTH / 8);
    const int hp = rest % (HEIGHT / 2);
    const int b = rest / (HEIGHT / 2);
    const int h0 = hp * 2;
    const int w0 = wg * 8;
    const int c0 = threadIdx.x * 4;

    float acc[16][4];
#pragma unroll
    for (int j = 0; j < 16; ++j)
#pragma unroll
        for (int q = 0; q < 4; ++q) acc[j][q] = 0.f;

#pragma unroll
    for (int i = 0; i < 4; ++i) {
        int hh = h0 - 1 + i;
        if (hh < 0 || hh >= HEIGHT) continue;
        const u16* rp = xz + ((size_t)(b * HEIGHT + hh) * WIDTH) * 2048 + c0;
        float a[10][4];
#pragma unroll
        for (int p = 0; p < 10; ++p) {
            int ww = w0 - 1 + p;
            if (ww >= 0 && ww < WIDTH) {
                ushort4 v = *reinterpret_cast<const ushort4*>(rp + (size_t)ww * 2048);
                a[p][0] = bf2f(v.x); a[p][1] = bf2f(v.y);
                a[p][2] = bf2f(v.z); a[p][3] = bf2f(v.w);
            } else {
                a[p][0] = a[p][1] = a[p][2] = a[p][3] = 0.f;
            }
        }
#pragma unroll
        for (int oh = 0; oh < 2; ++oh) {
            int kh = i - oh;
            if (kh < 0 || kh > 2) continue;
#pragma unroll
            for (int kw = 0; kw < 3; ++kw) {
                float4 kv = *reinterpret_cast<const float4*>(ck + (kh * 3 + kw) * DINNER + c0);
#pragma unroll
                for (int j = 0; j < 8; ++j) {
                    acc[oh * 8 + j][0] = fmaf(a[j + kw][0], kv.x, acc[oh * 8 + j][0]);
                    acc[oh * 8 + j][1] = fmaf(a[j + kw][1], kv.y, acc[oh * 8 + j][1]);
                    acc[oh * 8 + j][2] = fmaf(a[j + kw][2], kv.z, acc[oh * 8 + j][2]);
                    acc[oh * 8 + j][3] = fmaf(a[j + kw][3], kv.w, acc[oh * 8 + j][3]);
                }
            }
        }
    }
#pragma unroll
    for (int oh = 0; oh < 2; ++oh) {
        const size_t orow = (size_t)((b * HEIGHT + h0 + oh) * WIDTH + w0);
#pragma unroll
        for (int j = 0; j < 8; ++j) {
            ushort4 ov;
            ov.x = f2bf(acc[oh * 8 + j][0]); ov.y = f2bf(acc[oh * 8 + j][1]);
            ov.z = f2bf(acc[oh * 8 + j][2]); ov.w = f2bf(acc[oh * 8 + j][3]);
            *reinterpret_cast<ushort4*>(xc + (orow + j) * DINNER + c0) = ov;
        }
    }
}

// ---------------------------------------------------------------------------
// K3a: xp = xc @ WxpB^T via MFMA. M-tile=64, N=48, K=1024.
// ---------------------------------------------------------------------------
__global__ __launch_bounds__(256) void k_xproj(const u16* __restrict__ xc,
                                               const u16* __restrict__ WxpB,
                                               float* __restrict__ xp_out) {
    __shared__ u16 As[64 * 32];
    __shared__ u16 Bs[48 * 32];
    const int tid = threadIdx.x;
    const int l = tid & 63;
    const int w = tid >> 6;
    const int m0 = blockIdx.x * 64;
    const int kh = l >> 4, lr = l & 15;
    const int srow = w * 16 + (l >> 2);
    const int sc = l & 3;

    f32x4 acc[3];
    acc[0] = acc[1] = acc[2] = (f32x4){0.f, 0.f, 0.f, 0.f};

    for (int k0 = 0; k0 < 1024; k0 += 32) {
        {
            int cg = sc ^ ((srow >> 1) & 3);
            GLD16(xc + (size_t)(m0 + srow) * DINNER + k0 + cg * 8, As + w * 512);
            if (w < 3)
                GLD16(WxpB + (size_t)srow * 1024 + k0 + cg * 8, Bs + w * 512);
        }
        __syncthreads();
        int ar = w * 16 + lr;
        short8 af = *reinterpret_cast<const short8*>(As + ar * 32 + ((kh ^ ((ar >> 1) & 3)) * 8));
#pragma unroll
        for (int fn = 0; fn < 3; ++fn) {
            int br = fn * 16 + lr;
            short8 bf = *reinterpret_cast<const short8*>(Bs + br * 32 + ((kh ^ ((br >> 1) & 3)) * 8));
            acc[fn] = __builtin_amdgcn_mfma_f32_16x16x32_bf16(af, bf, acc[fn], 0, 0, 0);
        }
        __syncthreads();
    }
#pragma unroll
    for (int fn = 0; fn < 3; ++fn)
#pragma unroll
        for (int r = 0; r < 4; ++r) {
            int row = m0 + w * 16 + (l >> 4) * 4 + r;
            int col = fn * 16 + lr;
            if (col < NXP) xp_out[(size_t)row * NXP + col] = acc[fn][r];
        }
}

// ---------------------------------------------------------------------------
// K3b: dt = softplus(xp[:, :8] @ W_dt + b_dt) -> bf16 [row][1024]
// ---------------------------------------------------------------------------
__global__ __launch_bounds__(256) void k_dt(const float* __restrict__ xp,
                                            const float* __restrict__ W_dt,
                                            const float* __restrict__ b_dt,
                                            u16* __restrict__ dt_out) {
    int gid = blockIdx.x * 256 + threadIdx.x;
    int row = gid >> 7;
    int dj  = (gid & 127) * 8;
    const float* xr = xp + (size_t)row * NXP;
    float4 xa = *reinterpret_cast<const float4*>(xr);
    float4 xb = *reinterpret_cast<const float4*>(xr + 4);
    float xv[8] = {xa.x, xa.y, xa.z, xa.w, xb.x, xb.y, xb.z, xb.w};
    float a[8];
    {
        float4 b0 = *reinterpret_cast<const float4*>(b_dt + dj);
        float4 b1 = *reinterpret_cast<const float4*>(b_dt + dj + 4);
        a[0]=b0.x; a[1]=b0.y; a[2]=b0.z; a[3]=b0.w;
        a[4]=b1.x; a[5]=b1.y; a[6]=b1.z; a[7]=b1.w;
    }
#pragma unroll
    for (int j = 0; j < 8; ++j) {
        float4 w0 = *reinterpret_cast<const float4*>(W_dt + j * DINNER + dj);
        float4 w1 = *reinterpret_cast<const float4*>(W_dt + j * DINNER + dj + 4);
        a[0] = fmaf(xv[j], w0.x, a[0]); a[1] = fmaf(xv[j], w0.y, a[1]);
        a[2] = fmaf(xv[j], w0.z, a[2]); a[3] = fmaf(xv[j], w0.w, a[3]);
        a[4] = fmaf(xv[j], w1.x, a[4]); a[5] = fmaf(xv[j], w1.y, a[5]);
        a[6] = fmaf(xv[j], w1.z, a[6]); a[7] = fmaf(xv[j], w1.w, a[7]);
    }
    short8 o;
#pragma unroll
    for (int j = 0; j < 8; ++j) {
        float dt = fmaxf(a[j], 0.f) + log1pf(__expf(-fabsf(a[j])));
        o[j] = (short)f2bf(dt);
    }
    *reinterpret_cast<short8*>(dt_out + (size_t)row * DINNER + dj) = o;
}

// ---------------------------------------------------------------------------
// K3c: dtN = dt @ WdtNB^T + b_dtN via MFMA (M-tile=64, N=16, K=1024), then
// fused epilogue writes dnBC[row][32] = { dtN*B , C } (f32).
// ---------------------------------------------------------------------------
__global__ __launch_bounds__(256) void k_dtn(const u16* __restrict__ dtb,
                                             const u16* __restrict__ WdtNB,
                                             const float* __restrict__ b_dtN,
                                             const float* __restrict__ xp,
                                             float* __restrict__ dnBC) {
    __shared__ u16 As[64 * 32];
    __shared__ u16 Bs[16 * 32];
    const int tid = threadIdx.x;
    const int l = tid & 63;
    const int w = tid >> 6;
    const int m0 = blockIdx.x * 64;
    const int kh = l >> 4, lr = l & 15;
    const int srow = w * 16 + (l >> 2);
    const int sc = l & 3;

    f32x4 acc = (f32x4){0.f, 0.f, 0.f, 0.f};

    for (int k0 = 0; k0 < 1024; k0 += 32) {
        {
            int cg = sc ^ ((srow >> 1) & 3);
            GLD16(dtb + (size_t)(m0 + srow) * DINNER + k0 + cg * 8, As + w * 512);
            if (w == 0)
                GLD16(WdtNB + (size_t)srow * 1024 + k0 + cg * 8, Bs);
        }
        __syncthreads();
        int ar = w * 16 + lr;
        short8 af = *reinterpret_cast<const short8*>(As + ar * 32 + ((kh ^ ((ar >> 1) & 3)) * 8));
        short8 bf = *reinterpret_cast<const short8*>(Bs + lr * 32 + ((kh ^ ((lr >> 1) & 3)) * 8));
        acc = __builtin_amdgcn_mfma_f32_16x16x32_bf16(af, bf, acc, 0, 0, 0);
        __syncthreads();
    }
    float bn = b_dtN[lr];
#pragma unroll
    for (int r = 0; r < 4; ++r) {
        int row = m0 + w * 16 + (l >> 4) * 4 + r;
        float dn = acc[r] + bn;
        float Bv = xp[(size_t)row * NXP + DTRANK + lr];
        float Cv = xp[(size_t)row * NXP + DTRANK + DSTATE + lr];
        dnBC[(size_t)row * 32 + lr]      = dn * Bv;
        dnBC[(size_t)row * 32 + 16 + lr] = Cv;
    }
}

// ---------------------------------------------------------------------------
// K4a: chunk-local scan; lane = d, 8 f32x2 state pairs in registers (packed
// dual-FP32 VALU); A/B-rotated 1-iteration register prefetch. Q stored bf16.
// ---------------------------------------------------------------------------
#define P1_PAIR(K, UU) { \
    f32x2 e = dt2 * An22[K]; \
    f32x2 dA; dA[0] = EXP2(e[0]); dA[1] = EXP2(e[1]); \
    h2[K] = dA * h2[K] + (UU) * xt2; }

#define P1_BODY(T, DTC, XCC, DTN, XCN, PR) { \
    const float4* sv = pS + (size_t)(T) * 8; \
    float4 q0 = sv[0], q1 = sv[1], q2 = sv[2], q3 = sv[3]; \
    if (PR) { DTN = pdt[(size_t)((T) + 1) * DINNER]; \
              XCN = pxc[(size_t)((T) + 1) * DINNER]; } \
    float dt = bf2f(DTC), xt = bf2f(XCC); \
    sdt += dt; \
    f32x2 dt2 = {dt, dt}, xt2 = {xt, xt}; \
    f32x2 uu0 = {q0.x, q0.y}, uu1 = {q0.z, q0.w}; \
    f32x2 uu2 = {q1.x, q1.y}, uu3 = {q1.z, q1.w}; \
    f32x2 uu4 = {q2.x, q2.y}, uu5 = {q2.z, q2.w}; \
    f32x2 uu6 = {q3.x, q3.y}, uu7 = {q3.z, q3.w}; \
    P1_PAIR(0, uu0) P1_PAIR(1, uu1) P1_PAIR(2, uu2) P1_PAIR(3, uu3) \
    P1_PAIR(4, uu4) P1_PAIR(5, uu5) P1_PAIR(6, uu6) P1_PAIR(7, uu7) }

__global__ __launch_bounds__(256) void k_scan_p1(const u16* __restrict__ xc,
                                                 const u16* __restrict__ dtb,
                                                 const float* __restrict__ dnBC,
                                                 const float* __restrict__ A_log,
                                                 float* __restrict__ sdt_out,
                                                 u16* __restrict__ Qbuf) {
    const int tid = threadIdx.x;
    const int id  = blockIdx.x;
    const int swz = (id & 7) * ((NBATCH * NCH * 4) >> 3) + (id >> 3);
    const int quarter = swz & 3;
    const int bc = swz >> 2;            // b*NCH + c
    const int c = bc & (NCH - 1);
    const int b = bc >> 6;
    const int d = quarter * 256 + tid;

    f32x2 An22[8];
#pragma unroll
    for (int k = 0; k < 8; ++k) {
        An22[k][0] = -__expf(A_log[2 * k])     * 1.44269504f;
        An22[k][1] = -__expf(A_log[2 * k + 1]) * 1.44269504f;
    }

    f32x2 h2[8];
#pragma unroll
    for (int k = 0; k < 8; ++k) h2[k] = (f32x2){0.f, 0.f};
    float sdt = 0.f;

    const size_t row0 = (size_t)b * LSEQ + (size_t)c * TCH;
    const u16* pdt = dtb + row0 * DINNER + d;
    const u16* pxc = xc  + row0 * DINNER + d;
    const float4* pS = reinterpret_cast<const float4*>(dnBC + row0 * 32);

    u16 dtA = pdt[0], xcA = pxc[0];
    u16 dtB, xcB;

    for (int t = 0; t < TCH - 2; t += 2) {
        P1_BODY(t,     dtA, xcA, dtB, xcB, true)
        P1_BODY(t + 1, dtB, xcB, dtA, xcA, true)
    }
    P1_BODY(TCH - 2, dtA, xcA, dtB, xcB, true)
    P1_BODY(TCH - 1, dtB, xcB, dtA, xcA, false)

    sdt_out[(size_t)bc * DINNER + d] = sdt;
    size_t base = ((size_t)bc << 14) + d;   // [bc][n][d]
#pragma unroll
    for (int k = 0; k < 8; ++k) {
        Qbuf[base + (size_t)(2 * k) * DINNER]     = f2bf(h2[k][0]);
        Qbuf[base + (size_t)(2 * k + 1) * DINNER] = f2bf(h2[k][1]);
    }
}

// ---------------------------------------------------------------------------
// K4b: combine chunk states. thread = (b, n, d); NCH sequential steps.
// P recomputed from sdt; Q in bf16 (combine itself in f32).
// ---------------------------------------------------------------------------
__global__ __launch_bounds__(256) void k_scan_p2(const float* __restrict__ sdt,
                                                 const float* __restrict__ A_log,
                                                 u16* __restrict__ Qbuf) {
    int tid = blockIdx.x * 256 + threadIdx.x;
    int b = tid >> 14, rem = tid & 16383;
    int n = rem >> 10, d = rem & 1023;
    float An2 = -__expf(A_log[n]) * 1.44269504f;
    float h = 0.f;
    for (int c = 0; c < NCH; ++c) {
        int bc = b * NCH + c;
        float P = EXP2(sdt[(size_t)bc * DINNER + d] * An2);
        size_t idx = ((size_t)bc << 14) + rem;
        float q = bf2f(Qbuf[idx]);
        Qbuf[idx] = f2bf(h);           // h_start for chunk c
        h = fmaf(P, h, q);
    }
}

// ---------------------------------------------------------------------------
// K4c: re-run chunk from true h_start; packed dual-FP32 inner loop;
// y = C·h + D*x written to xz y-half. Q in bf16.
// ---------------------------------------------------------------------------
#define P3_PAIR(K, UU, CC, YS) { \
    f32x2 e = dt2 * An22[K]; \
    f32x2 dA; dA[0] = EXP2(e[0]); dA[1] = EXP2(e[1]); \
    h2[K] = dA * h2[K] + (UU) * xt2; \
    YS = h2[K] * (CC) + YS; }

#define P3_BODY(T, DTC, XCC, DTN, XCN, PR) { \
    const float4* sv = pS + (size_t)(T) * 8; \
    float4 q0 = sv[0], q1 = sv[1], q2 = sv[2], q3 = sv[3]; \
    float4 p0 = sv[4], p1 = sv[5], p2 = sv[6], p3 = sv[7]; \
    if (PR) { DTN = pdt[(size_t)((T) + 1) * DINNER]; \
              XCN = pxc[(size_t)((T) + 1) * DINNER]; } \
    float dt = bf2f(DTC), xt = bf2f(XCC); \
    f32x2 dt2 = {dt, dt}, xt2 = {xt, xt}; \
    f32x2 uu0 = {q0.x, q0.y}, uu1 = {q0.z, q0.w}; \
    f32x2 uu2 = {q1.x, q1.y}, uu3 = {q1.z, q1.w}; \
    f32x2 uu4 = {q2.x, q2.y}, uu5 = {q2.z, q2.w}; \
    f32x2 uu6 = {q3.x, q3.y}, uu7 = {q3.z, q3.w}; \
    f32x2 cc0 = {p0.x, p0.y}, cc1 = {p0.z, p0.w}; \
    f32x2 cc2 = {p1.x, p1.y}, cc3 = {p1.z, p1.w}; \
    f32x2 cc4 = {p2.x, p2.y}, cc5 = {p2.z, p2.w}; \
    f32x2 cc6 = {p3.x, p3.y}, cc7 = {p3.z, p3.w}; \
    f32x2 ysA = {Dsk * xt, 0.f}, ysB = {0.f, 0.f}; \
    P3_PAIR(0, uu0, cc0, ysA) P3_PAIR(1, uu1, cc1, ysB) \
    P3_PAIR(2, uu2, cc2, ysA) P3_PAIR(3, uu3, cc3, ysB) \
    P3_PAIR(4, uu4, cc4, ysA) P3_PAIR(5, uu5, cc5, ysB) \
    P3_PAIR(6, uu6, cc6, ysA) P3_PAIR(7, uu7, cc7, ysB) \
    ybuf[(row0 + (T)) * 2048 + d] = f2bf((ysA[0] + ysA[1]) + (ysB[0] + ysB[1])); }

__global__ __launch_bounds__(256) void k_scan_p3(const u16* __restrict__ xc,
                                                 const u16* __restrict__ dtb,
                                                 const float* __restrict__ dnBC,
                                                 const float* __restrict__ A_log,
                                                 const float* __restrict__ Dskip,
                                                 const u16* __restrict__ Qbuf,
                                                 u16* __restrict__ ybuf) {
    const int tid = threadIdx.x;
    const int id  = blockIdx.x;
    const int swz = (id & 7) * ((NBATCH * NCH * 4) >> 3) + (id >> 3);
    const int quarter = swz & 3;
    const int bc = swz >> 2;
    const int c = bc & (NCH - 1);
    const int b = bc >> 6;
    const int d = quarter * 256 + tid;

    f32x2 An22[8];
#pragma unroll
    for (int k = 0; k < 8; ++k) {
        An22[k][0] = -__expf(A_log[2 * k])     * 1.44269504f;
        An22[k][1] = -__expf(A_log[2 * k + 1]) * 1.44269504f;
    }

    f32x2 h2[8];
    size_t base = ((size_t)bc << 14) + d;   // [bc][n][d]
#pragma unroll
    for (int k = 0; k < 8; ++k) {
        h2[k][0] = bf2f(Qbuf[base + (size_t)(2 * k) * DINNER]);
        h2[k][1] = bf2f(Qbuf[base + (size_t)(2 * k + 1) * DINNER]);
    }
    float Dsk = Dskip[d];

    const size_t row0 = (size_t)b * LSEQ + (size_t)c * TCH;
    const u16* pdt = dtb + row0 * DINNER + d;
    const u16* pxc = xc  + row0 * DINNER + d;
    const float4* pS = reinterpret_cast<const float4*>(dnBC + row0 * 32);

    u16 dtA = pdt[0], xcA = pxc[0];
    u16 dtB, xcB;

    for (int t = 0; t < TCH - 2; t += 2) {
        P3_BODY(t,     dtA, xcA, dtB, xcB, true)
        P3_BODY(t + 1, dtB, xcB, dtA, xcA, true)
    }
    P3_BODY(TCH - 2, dtA, xcA, dtB, xcB, true)
    P3_BODY(TCH - 1, dtB, xcB, dtA, xcA, false)
}

// ---------------------------------------------------------------------------
// K5: LayerNorm(y) * ln_g + ln_b, then * silu(z). Wave-per-row (no LDS,
// no barrier): 4608 blocks x 4 waves; lane owns 16 contiguous channels.
// ---------------------------------------------------------------------------
__global__ __launch_bounds__(256) void k_ln_gate(u16* __restrict__ xz,
                                                 const float* __restrict__ ln_g,
                                                 const float* __restrict__ ln_b) {
    const int wv = threadIdx.x >> 6, l = threadIdx.x & 63;
    const int row = blockIdx.x * 4 + wv;
    u16* yrow = xz + (size_t)row * 2048;
    const int c0 = l * 16;

    short8 v0 = *reinterpret_cast<const short8*>(yrow + c0);
    short8 v1 = *reinterpret_cast<const short8*>(yrow + c0 + 8);
    float y[16];
#pragma unroll
    for (int j = 0; j < 8; ++j) {
        y[j]     = bf2f((u16)v0[j]);
        y[8 + j] = bf2f((u16)v1[j]);
    }
    float s = 0.f, q = 0.f;
#pragma unroll
    for (int j = 0; j < 16; ++j) { s += y[j]; q = fmaf(y[j], y[j], q); }
#pragma unroll
    for (int m = 32; m; m >>= 1) {
        s += __shfl_xor(s, m, 64);
        q += __shfl_xor(q, m, 64);
    }
    float mu = s * (1.f / DINNER);
    float var = q * (1.f / DINNER) - mu * mu;
    float rstd = rsqrtf(var + 1e-5f);

    short8 z0 = *reinterpret_cast<const short8*>(yrow + DINNER + c0);
    short8 z1 = *reinterpret_cast<const short8*>(yrow + DINNER + c0 + 8);
    float4 lg0 = *reinterpret_cast<const float4*>(ln_g + c0);
    float4 lg1 = *reinterpret_cast<const float4*>(ln_g + c0 + 4);
    float4 lg2 = *reinterpret_cast<const float4*>(ln_g + c0 + 8);
    float4 lg3 = *reinterpret_cast<const float4*>(ln_g + c0 + 12);
    float4 lb0 = *reinterpret_cast<const float4*>(ln_b + c0);
    float4 lb1 = *reinterpret_cast<const float4*>(ln_b + c0 + 4);
    float4 lb2 = *reinterpret_cast<const float4*>(ln_b + c0 + 8);
    float4 lb3 = *reinterpret_cast<const float4*>(ln_b + c0 + 12);
    float lg[16] = {lg0.x,lg0.y,lg0.z,lg0.w, lg1.x,lg1.y,lg1.z,lg1.w,
                    lg2.x,lg2.y,lg2.z,lg2.w, lg3.x,lg3.y,lg3.z,lg3.w};
    float lb[16] = {lb0.x,lb0.y,lb0.z,lb0.w, lb1.x,lb1.y,lb1.z,lb1.w,
                    lb2.x,lb2.y,lb2.z,lb2.w, lb3.x,lb3.y,lb3.z,lb3.w};

    short8 o0, o1;
#pragma unroll
    for (int j = 0; j < 16; ++j) {
        float zv = bf2f((u16)((j < 8) ? z0[j] : z1[j - 8]));
        float g = ((y[j] - mu) * rstd * lg[j] + lb[j]) * (zv / (1.f + __expf(-zv)));
        if (j < 8) o0[j] = (short)f2bf(g); else o1[j - 8] = (short)f2bf(g);
    }
    *reinterpret_cast<short8*>(yrow + c0)     = o0;
    *reinterpret_cast<short8*>(yrow + c0 + 8) = o1;
}

// ---------------------------------------------------------------------------
extern "C" void kernel_launch(void* const* d_in, const int* in_sizes, int n_in,
                              void* d_out, int out_size, void* d_ws, size_t ws_size,
                              hipStream_t stream) {
    const float* x       = (const float*)d_in[0];
    const float* W_in    = (const float*)d_in[1];
    const float* conv_k  = (const float*)d_in[2];
    const float* W_xproj = (const float*)d_in[3];
    const float* W_dt    = (const float*)d_in[4];
    const float* b_dt    = (const float*)d_in[5];
    const float* A_log   = (const float*)d_in[6];
    const float* Dskip   = (const float*)d_in[7];
    const float* W_dtN   = (const float*)d_in[8];
    const float* b_dtN   = (const float*)d_in[9];
    const float* ln_g    = (const float*)d_in[10];
    const float* ln_b    = (const float*)d_in[11];
    const float* W_out   = (const float*)d_in[12];
    const float* b_out   = (const float*)d_in[13];
    float* out = (float*)d_out;

    char* ws = (char*)d_ws;
    size_t off = 0;
    u16*   xz    = (u16*)(ws + off); off += (size_t)NROWS * 2048 * 2;   // 75.5 MB
    u16*   xc    = (u16*)(ws + off); off += (size_t)NROWS * 1024 * 2;   // 37.7 MB
    u16*   dtb   = (u16*)(ws + off); off += (size_t)NROWS * 1024 * 2;   // 37.7 MB
    float* xpb   = (float*)(ws + off); off += (size_t)NROWS * NXP * 4;  // 2.95 MB
    float* dnBC  = (float*)(ws + off); off += (size_t)NROWS * 32 * 4;   // 2.36 MB
    // scratch union: xbf (18.9 MB) dead before Qbuf (bf16, 16.8 MB) written
    char*  scr   = ws + off; off += (size_t)NROWS * DMODEL * 2;         // 18.9 MB
    u16*   xbf   = (u16*)scr;
    u16*   Qbuf  = (u16*)scr;
    // sdt (2 MB) overlays xpb: xp is dead after k_dtn (scan consumes dnBC only)
    float* sdtb  = xpb;
    u16*   WinT  = (u16*)(ws + off); off += (size_t)2048 * 512 * 2;
    u16*   WoutT = (u16*)(ws + off); off += (size_t)512 * 1024 * 2;
    u16*   WxpB  = (u16*)(ws + off); off += (size_t)48 * 1024 * 2;
    u16*   WdtNB = (u16*)(ws + off); off += (size_t)16 * 1024 * 2;

    k_prep<<<9216 + 6400, 256, 0, stream>>>(x, W_in, W_out, W_xproj, W_dtN,
                                            xbf, WinT, WoutT, WxpB, WdtNB);
    k_gemm_mfma<512, 512, 512, 2048, false>
        <<<dim3(2048 / 128, NROWS / 128), 256, 0, stream>>>(xbf, WinT, nullptr, xz);
    k_conv<<<NBATCH * (HEIGHT / 2) * (WIDTH / 8), 256, 0, stream>>>(xz, conv_k, xc);
    k_xproj<<<NROWS / 64, 256, 0, stream>>>(xc, WxpB, xpb);
    k_dt<<<(NROWS * DINNER / 8) / 256, 256, 0, stream>>>(xpb, W_dt, b_dt, dtb);
    k_dtn<<<NROWS / 64, 256, 0, stream>>>(dtb, WdtNB, b_dtN, xpb, dnBC);
    k_scan_p1<<<NBATCH * NCH * 4, 256, 0, stream>>>(xc, dtb, dnBC, A_log,
                                                    sdtb, Qbuf);
    k_scan_p2<<<(NBATCH * DINNER * DSTATE) / 256, 256, 0, stream>>>(sdtb, A_log, Qbuf);
    k_scan_p3<<<NBATCH * NCH * 4, 256, 0, stream>>>(xc, dtb, dnBC, A_log,
                                                    Dskip, Qbuf, xz);
    k_ln_gate<<<NROWS / 4, 256, 0, stream>>>(xz, ln_g, ln_b);
    k_gemm_mfma<1024, 2048, 1024, 512, true>
        <<<dim3(DMODEL / 128, NROWS / 128), 256, 0, stream>>>(xz, WoutT, b_out, out);
}